// Round 1
// baseline (2998.238 us; speedup 1.0000x reference)
//
#include <hip/hip_runtime.h>
#include <math.h>

// TransformerBlock: N=2048 tokens, D=1024, H=16, DK=DV=64, FF=4096, fp32.
// Round 0: correctness-first fp32 tiled-GEMM pipeline.
//   qkv -> per-head {scores(causal-lower), softmax(zeros above diag), PV} ->
//   o-proj(+x resid) -> LN1 -> FFN1(relu) -> FFN2(relu) -> LN2(h1+ff2) -> out

#define NTOK   2048
#define DMODEL 1024
#define NHEAD  16
#define DHEAD  64
#define DFF    4096
#define LNEPS  1e-5f

// ---------------- generic 64x64-tile fp32 GEMM ----------------
// C[row0:+64, col0:+64] = act(alpha * A@opB + bias + resid)
// BT==0: B is [K x N] row-major (ldb). BT==1: B is [N x K] row-major (use B[col][k]).
template<int BT, int RELU, int BIAS, int RESID>
__device__ __forceinline__ void gemm_tile64(
    const float* __restrict__ A, int lda,
    const float* __restrict__ B, int ldb,
    float* __restrict__ C, int ldc,
    int K, float alpha,
    const float* __restrict__ bias,
    const float* __restrict__ resid, int ldr,
    int row0, int col0)
{
    __shared__ __align__(16) float As[64][20];   // pad 20: 16B-aligned rows, conflict-free reads
    __shared__ __align__(16) float Bs[16][68];   // pad 68: 16B-aligned rows, 2-way max
    const int tid = threadIdx.x;                 // 256 threads
    const int tx = tid & 15, ty = tid >> 4;
    float acc[4][4] = {};

    for (int k0 = 0; k0 < K; k0 += 16) {
        // A tile: 64 rows x 16 k
        {
            int r  = tid >> 2;
            int kk = (tid & 3) << 2;
            float4 v4 = *reinterpret_cast<const float4*>(A + (size_t)(row0 + r) * lda + k0 + kk);
            *reinterpret_cast<float4*>(&As[r][kk]) = v4;
        }
        if (BT == 0) {
            int kk = tid >> 4;
            int c  = (tid & 15) << 2;
            float4 v4 = *reinterpret_cast<const float4*>(B + (size_t)(k0 + kk) * ldb + col0 + c);
            *reinterpret_cast<float4*>(&Bs[kk][c]) = v4;
        } else {
            int c  = tid >> 2;
            int kk = (tid & 3) << 2;
            float4 v4 = *reinterpret_cast<const float4*>(B + (size_t)(col0 + c) * ldb + k0 + kk);
            Bs[kk+0][c] = v4.x; Bs[kk+1][c] = v4.y; Bs[kk+2][c] = v4.z; Bs[kk+3][c] = v4.w;
        }
        __syncthreads();
        #pragma unroll
        for (int kk = 0; kk < 16; ++kk) {
            float av[4];
            #pragma unroll
            for (int i = 0; i < 4; ++i) av[i] = As[ty*4 + i][kk];
            float4 b4 = *reinterpret_cast<const float4*>(&Bs[kk][tx*4]);
            float bv[4] = {b4.x, b4.y, b4.z, b4.w};
            #pragma unroll
            for (int i = 0; i < 4; ++i)
                #pragma unroll
                for (int j = 0; j < 4; ++j)
                    acc[i][j] = fmaf(av[i], bv[j], acc[i][j]);
        }
        __syncthreads();
    }

    #pragma unroll
    for (int i = 0; i < 4; ++i) {
        int r = row0 + ty*4 + i;
        #pragma unroll
        for (int j = 0; j < 4; ++j) {
            int c = col0 + tx*4 + j;
            float val = acc[i][j] * alpha;
            if (BIAS)  val += bias[c];
            if (RESID) val += resid[(size_t)r * ldr + c];
            if (RELU)  val = fmaxf(val, 0.0f);
            C[(size_t)r * ldc + c] = val;
        }
    }
}

// ---------------- wrappers ----------------
__global__ __launch_bounds__(256) void qkv_kernel(
    const float* __restrict__ x,
    const float* __restrict__ wq, const float* __restrict__ wk, const float* __restrict__ wv,
    float* __restrict__ q, float* __restrict__ k, float* __restrict__ v)
{
    int h = blockIdx.y, p = blockIdx.z;
    const float* W = (p == 0 ? wq : p == 1 ? wk : wv) + (size_t)h * DMODEL * DHEAD;
    float*       O = (p == 0 ? q  : p == 1 ? k  : v ) + (size_t)h * NTOK * DHEAD;
    gemm_tile64<0,0,0,0>(x, DMODEL, W, DHEAD, O, DHEAD, DMODEL, 1.0f,
                         nullptr, nullptr, 0, blockIdx.x * 64, 0);
}

__global__ __launch_bounds__(256) void scores_kernel(
    const float* __restrict__ q, const float* __restrict__ k,
    float* __restrict__ S, int h)
{
    int jt = blockIdx.x, it = blockIdx.y;
    if (jt > it) return;   // fully-masked tile: softmax never reads above diagonal
    const float* qh = q + (size_t)h * NTOK * DHEAD;
    const float* kh = k + (size_t)h * NTOK * DHEAD;
    gemm_tile64<1,0,0,0>(qh, DHEAD, kh, DHEAD, S, NTOK, DHEAD, 0.125f,
                         nullptr, nullptr, 0, it * 64, jt * 64);
}

__global__ __launch_bounds__(256) void softmax_causal(float* __restrict__ S)
{
    int row = blockIdx.x, tid = threadIdx.x;
    __shared__ float buf[NTOK];
    __shared__ float red[256];
    int nvalid = row + 1;

    float m = -INFINITY;
    for (int j = tid; j < nvalid; j += 256) { float s = S[(size_t)row * NTOK + j]; buf[j] = s; m = fmaxf(m, s); }
    red[tid] = m; __syncthreads();
    for (int s = 128; s > 0; s >>= 1) { if (tid < s) red[tid] = fmaxf(red[tid], red[tid + s]); __syncthreads(); }
    m = red[0]; __syncthreads();

    float sum = 0.0f;
    for (int j = tid; j < nvalid; j += 256) { float p = __expf(buf[j] - m); buf[j] = p; sum += p; }
    red[tid] = sum; __syncthreads();
    for (int s = 128; s > 0; s >>= 1) { if (tid < s) red[tid] += red[tid + s]; __syncthreads(); }
    float inv = 1.0f / red[0];

    for (int j = tid; j < NTOK; j += 256)
        S[(size_t)row * NTOK + j] = (j < nvalid) ? buf[j] * inv : 0.0f;
}

__global__ __launch_bounds__(256) void pv_kernel(
    const float* __restrict__ S, const float* __restrict__ v,
    float* __restrict__ concat, int h)
{
    int it = blockIdx.y;
    int kmax = (it + 1) * 64;  // P is zero above the diagonal; only lower K needed
    const float* vh = v + (size_t)h * NTOK * DHEAD;
    gemm_tile64<0,0,0,0>(S, NTOK, vh, DHEAD, concat + h * DHEAD, DMODEL, kmax, 1.0f,
                         nullptr, nullptr, 0, it * 64, 0);
}

__global__ __launch_bounds__(256) void oproj_kernel(
    const float* __restrict__ concat, const float* __restrict__ wo,
    const float* __restrict__ x, float* __restrict__ res1)
{
    gemm_tile64<0,0,0,1>(concat, DMODEL, wo, DMODEL, res1, DMODEL, DMODEL, 1.0f,
                         nullptr, x, DMODEL, blockIdx.y * 64, blockIdx.x * 64);
}

__global__ __launch_bounds__(256) void ffn1_kernel(
    const float* __restrict__ h1, const float* __restrict__ w1,
    const float* __restrict__ b1, float* __restrict__ ff1)
{
    gemm_tile64<0,1,1,0>(h1, DMODEL, w1, DFF, ff1, DFF, DMODEL, 1.0f,
                         b1, nullptr, 0, blockIdx.y * 64, blockIdx.x * 64);
}

__global__ __launch_bounds__(256) void ffn2_kernel(
    const float* __restrict__ ff1, const float* __restrict__ w2,
    const float* __restrict__ b2, float* __restrict__ ff2)
{
    gemm_tile64<0,1,1,0>(ff1, DFF, w2, DMODEL, ff2, DMODEL, DFF, 1.0f,
                         b2, nullptr, 0, blockIdx.y * 64, blockIdx.x * 64);
}

// LN over D=1024. ADD==1: input = X + Y.
template<int ADD>
__global__ __launch_bounds__(256) void layernorm_k(
    const float* __restrict__ X, const float* __restrict__ Y,
    const float* __restrict__ g, const float* __restrict__ b,
    float* __restrict__ out)
{
    int row = blockIdx.x, tid = threadIdx.x;
    __shared__ float red[256];
    float vals[4];
    float s = 0.0f;
    #pragma unroll
    for (int i = 0; i < 4; ++i) {
        int c = tid + i * 256;
        float v = X[(size_t)row * DMODEL + c];
        if (ADD) v += Y[(size_t)row * DMODEL + c];
        vals[i] = v; s += v;
    }
    red[tid] = s; __syncthreads();
    for (int st = 128; st > 0; st >>= 1) { if (tid < st) red[tid] += red[tid + st]; __syncthreads(); }
    float mu = red[0] * (1.0f / DMODEL);
    __syncthreads();

    float vs = 0.0f;
    #pragma unroll
    for (int i = 0; i < 4; ++i) { float d = vals[i] - mu; vs += d * d; }
    red[tid] = vs; __syncthreads();
    for (int st = 128; st > 0; st >>= 1) { if (tid < st) red[tid] += red[tid + st]; __syncthreads(); }
    float rstd = rsqrtf(red[0] * (1.0f / DMODEL) + LNEPS);

    #pragma unroll
    for (int i = 0; i < 4; ++i) {
        int c = tid + i * 256;
        out[(size_t)row * DMODEL + c] = (vals[i] - mu) * rstd * g[c] + b[c];
    }
}

// ---------------- launch ----------------
extern "C" void kernel_launch(void* const* d_in, const int* in_sizes, int n_in,
                              void* d_out, int out_size, void* d_ws, size_t ws_size,
                              hipStream_t stream)
{
    const float* x    = (const float*)d_in[0];
    const float* wq   = (const float*)d_in[1];
    const float* wk   = (const float*)d_in[2];
    const float* wv   = (const float*)d_in[3];
    const float* wo   = (const float*)d_in[4];
    const float* ln1g = (const float*)d_in[5];
    const float* ln1b = (const float*)d_in[6];
    const float* w1   = (const float*)d_in[7];
    const float* b1   = (const float*)d_in[8];
    const float* w2   = (const float*)d_in[9];
    const float* b2   = (const float*)d_in[10];
    const float* ln2g = (const float*)d_in[11];
    const float* ln2b = (const float*)d_in[12];
    float* out = (float*)d_out;

    char* ws = (char*)d_ws;
    const size_t MB = 1024 * 1024;
    float* q      = (float*)(ws + 0 * MB);   // 8 MiB  [H][N][DK]
    float* k      = (float*)(ws + 8 * MB);   // 8 MiB
    float* v      = (float*)(ws + 16 * MB);  // 8 MiB
    float* S      = (float*)(ws + 24 * MB);  // 16 MiB [N][N], reused per head
    float* concat = (float*)(ws + 40 * MB);  // 8 MiB  [N][H*DV]
    float* res1   = (float*)(ws + 48 * MB);  // 8 MiB  x+mha; later reused as ff2
    float* h1     = (float*)(ws + 56 * MB);  // 8 MiB  LN1 output
    float* ff1    = (float*)(ws + 0 * MB);   // 32 MiB, aliases q/k/v/S (dead by then)
    float* ff2    = res1;                    // res1 dead after LN1

    dim3 blk(256);

    qkv_kernel<<<dim3(NTOK / 64, NHEAD, 3), blk, 0, stream>>>(x, wq, wk, wv, q, k, v);

    for (int h = 0; h < NHEAD; ++h) {
        scores_kernel<<<dim3(NTOK / 64, NTOK / 64), blk, 0, stream>>>(q, k, S, h);
        softmax_causal<<<dim3(NTOK), blk, 0, stream>>>(S);
        pv_kernel<<<dim3(1, NTOK / 64), blk, 0, stream>>>(S, v, concat, h);
    }

    oproj_kernel<<<dim3(DMODEL / 64, NTOK / 64), blk, 0, stream>>>(concat, wo, x, res1);
    layernorm_k<0><<<dim3(NTOK), blk, 0, stream>>>(res1, nullptr, ln1g, ln1b, h1);
    ffn1_kernel<<<dim3(DFF / 64, NTOK / 64), blk, 0, stream>>>(h1, w1, b1, ff1);
    ffn2_kernel<<<dim3(DMODEL / 64, NTOK / 64), blk, 0, stream>>>(ff1, w2, b2, ff2);
    layernorm_k<1><<<dim3(NTOK), blk, 0, stream>>>(h1, ff2, ln2g, ln2b, out);
}

// Round 2
// 1007.835 us; speedup vs baseline: 2.9749x; 2.9749x over previous
//
#include <hip/hip_runtime.h>
#include <math.h>

// TransformerBlock N=2048, D=1024, H=16, DK=DV=64, FF=4096, fp32.
// Round 1: batched fp32 flash attention (1 launch) replaces per-head
// scores/softmax/pv (48 latency-bound launches). GEMMs unchanged.

#define NTOK   2048
#define DMODEL 1024
#define NHEAD  16
#define DHEAD  64
#define DFF    4096
#define LNEPS  1e-5f

// ---------------- generic 64x64-tile fp32 GEMM ----------------
template<int BT, int RELU, int BIAS, int RESID>
__device__ __forceinline__ void gemm_tile64(
    const float* __restrict__ A, int lda,
    const float* __restrict__ B, int ldb,
    float* __restrict__ C, int ldc,
    int K, float alpha,
    const float* __restrict__ bias,
    const float* __restrict__ resid, int ldr,
    int row0, int col0)
{
    __shared__ __align__(16) float As[64][20];
    __shared__ __align__(16) float Bs[16][68];
    const int tid = threadIdx.x;
    const int tx = tid & 15, ty = tid >> 4;
    float acc[4][4] = {};

    for (int k0 = 0; k0 < K; k0 += 16) {
        {
            int r  = tid >> 2;
            int kk = (tid & 3) << 2;
            float4 v4 = *reinterpret_cast<const float4*>(A + (size_t)(row0 + r) * lda + k0 + kk);
            *reinterpret_cast<float4*>(&As[r][kk]) = v4;
        }
        if (BT == 0) {
            int kk = tid >> 4;
            int c  = (tid & 15) << 2;
            float4 v4 = *reinterpret_cast<const float4*>(B + (size_t)(k0 + kk) * ldb + col0 + c);
            *reinterpret_cast<float4*>(&Bs[kk][c]) = v4;
        } else {
            int c  = tid >> 2;
            int kk = (tid & 3) << 2;
            float4 v4 = *reinterpret_cast<const float4*>(B + (size_t)(col0 + c) * ldb + k0 + kk);
            Bs[kk+0][c] = v4.x; Bs[kk+1][c] = v4.y; Bs[kk+2][c] = v4.z; Bs[kk+3][c] = v4.w;
        }
        __syncthreads();
        #pragma unroll
        for (int kk = 0; kk < 16; ++kk) {
            float av[4];
            #pragma unroll
            for (int i = 0; i < 4; ++i) av[i] = As[ty*4 + i][kk];
            float4 b4 = *reinterpret_cast<const float4*>(&Bs[kk][tx*4]);
            float bv[4] = {b4.x, b4.y, b4.z, b4.w};
            #pragma unroll
            for (int i = 0; i < 4; ++i)
                #pragma unroll
                for (int j = 0; j < 4; ++j)
                    acc[i][j] = fmaf(av[i], bv[j], acc[i][j]);
        }
        __syncthreads();
    }

    #pragma unroll
    for (int i = 0; i < 4; ++i) {
        int r = row0 + ty*4 + i;
        #pragma unroll
        for (int j = 0; j < 4; ++j) {
            int c = col0 + tx*4 + j;
            float val = acc[i][j] * alpha;
            if (BIAS)  val += bias[c];
            if (RESID) val += resid[(size_t)r * ldr + c];
            if (RELU)  val = fmaxf(val, 0.0f);
            C[(size_t)r * ldc + c] = val;
        }
    }
}

__global__ __launch_bounds__(256) void qkv_kernel(
    const float* __restrict__ x,
    const float* __restrict__ wq, const float* __restrict__ wk, const float* __restrict__ wv,
    float* __restrict__ q, float* __restrict__ k, float* __restrict__ v)
{
    int h = blockIdx.y, p = blockIdx.z;
    const float* W = (p == 0 ? wq : p == 1 ? wk : wv) + (size_t)h * DMODEL * DHEAD;
    float*       O = (p == 0 ? q  : p == 1 ? k  : v ) + (size_t)h * NTOK * DHEAD;
    gemm_tile64<0,0,0,0>(x, DMODEL, W, DHEAD, O, DHEAD, DMODEL, 1.0f,
                         nullptr, nullptr, 0, blockIdx.x * 64, 0);
}

// ---------------- batched fp32 flash attention ----------------
// grid (N/64, H), 256 threads. Q tile in LDS; per kv-tile: K^T staged,
// V staged, S in regs (4x4/thread), online softmax, P->LDS (K buffer
// reused), PV accumulate. Output written directly to concat layout.
__global__ __launch_bounds__(256) void flash_attn(
    const float* __restrict__ q, const float* __restrict__ k, const float* __restrict__ v,
    float* __restrict__ concat)
{
    const int it = blockIdx.x, h = blockIdx.y;
    const float* qh = q + (size_t)h * NTOK * DHEAD;
    const float* kh = k + (size_t)h * NTOK * DHEAD;
    const float* vh = v + (size_t)h * NTOK * DHEAD;

    __shared__ __align__(16) float Qs[64][68];
    __shared__ __align__(16) float KPs[64][68];  // K^T during QK, then P during PV
    __shared__ __align__(16) float Vs[64][68];

    const int tid = threadIdx.x;
    const int tx = tid & 15, ty = tid >> 4;

    // stage Q tile once: 64 rows x 64 cols
    #pragma unroll
    for (int m = 0; m < 4; ++m) {
        int idx = tid + m * 256;
        int r = idx >> 4, c4 = (idx & 15) << 2;
        float4 v4 = *reinterpret_cast<const float4*>(qh + (size_t)(it*64 + r) * DHEAD + c4);
        *reinterpret_cast<float4*>(&Qs[r][c4]) = v4;
    }

    float o[4][4] = {};
    float m_run[4], l_run[4];
    #pragma unroll
    for (int i = 0; i < 4; ++i) { m_run[i] = -INFINITY; l_run[i] = 0.0f; }

    for (int jt = 0; jt <= it; ++jt) {
        __syncthreads();   // previous iter's readers of KPs/Vs done (also covers Q stage)
        // stage K transposed + V direct
        #pragma unroll
        for (int m = 0; m < 4; ++m) {
            int idx = tid + m * 256;
            int r = idx >> 4, c4 = (idx & 15) << 2;
            float4 kv = *reinterpret_cast<const float4*>(kh + (size_t)(jt*64 + r) * DHEAD + c4);
            KPs[c4+0][r] = kv.x; KPs[c4+1][r] = kv.y; KPs[c4+2][r] = kv.z; KPs[c4+3][r] = kv.w;
            float4 vv = *reinterpret_cast<const float4*>(vh + (size_t)(jt*64 + r) * DHEAD + c4);
            *reinterpret_cast<float4*>(&Vs[r][c4]) = vv;
        }
        __syncthreads();

        // S = 0.125 * Q @ K^T   (4x4 per thread)
        float s[4][4] = {};
        #pragma unroll 4
        for (int kk = 0; kk < 64; kk += 4) {
            float qa[4][4], kb[4][4];
            #pragma unroll
            for (int i = 0; i < 4; ++i) {
                float4 t = *reinterpret_cast<const float4*>(&Qs[ty*4 + i][kk]);
                qa[i][0] = t.x; qa[i][1] = t.y; qa[i][2] = t.z; qa[i][3] = t.w;
            }
            #pragma unroll
            for (int m = 0; m < 4; ++m) {
                float4 t = *reinterpret_cast<const float4*>(&KPs[kk + m][tx*4]);
                kb[m][0] = t.x; kb[m][1] = t.y; kb[m][2] = t.z; kb[m][3] = t.w;
            }
            #pragma unroll
            for (int i = 0; i < 4; ++i)
                #pragma unroll
                for (int m = 0; m < 4; ++m)
                    #pragma unroll
                    for (int j = 0; j < 4; ++j)
                        s[i][j] = fmaf(qa[i][m], kb[m][j], s[i][j]);
        }

        // causal mask on the diagonal tile
        if (jt == it) {
            #pragma unroll
            for (int i = 0; i < 4; ++i)
                #pragma unroll
                for (int j = 0; j < 4; ++j)
                    if (tx*4 + j > ty*4 + i) s[i][j] = -INFINITY;
        }

        // online softmax (row r = ty*4+i spans tx lanes within one wave)
        float p_[4][4];
        #pragma unroll
        for (int i = 0; i < 4; ++i) {
            float pm = -INFINITY;
            #pragma unroll
            for (int j = 0; j < 4; ++j) pm = fmaxf(pm, s[i][j] * 0.125f);
            pm = fmaxf(pm, __shfl_xor(pm, 1));
            pm = fmaxf(pm, __shfl_xor(pm, 2));
            pm = fmaxf(pm, __shfl_xor(pm, 4));
            pm = fmaxf(pm, __shfl_xor(pm, 8));
            float mnew = fmaxf(m_run[i], pm);
            float corr = __expf(m_run[i] - mnew);
            float rs = 0.0f;
            #pragma unroll
            for (int j = 0; j < 4; ++j) {
                float pv_ = __expf(s[i][j] * 0.125f - mnew);
                p_[i][j] = pv_; rs += pv_;
            }
            rs += __shfl_xor(rs, 1);
            rs += __shfl_xor(rs, 2);
            rs += __shfl_xor(rs, 4);
            rs += __shfl_xor(rs, 8);
            l_run[i] = l_run[i] * corr + rs;
            m_run[i] = mnew;
            #pragma unroll
            for (int j = 0; j < 4; ++j) o[i][j] *= corr;
        }

        __syncthreads();   // all waves finished reading K^T from KPs
        #pragma unroll
        for (int i = 0; i < 4; ++i) {
            float4 t; t.x = p_[i][0]; t.y = p_[i][1]; t.z = p_[i][2]; t.w = p_[i][3];
            *reinterpret_cast<float4*>(&KPs[ty*4 + i][tx*4]) = t;  // P (intra-wave rows)
        }

        // O += P @ V
        #pragma unroll 4
        for (int p = 0; p < 64; p += 4) {
            float pa[4][4], vb[4][4];
            #pragma unroll
            for (int i = 0; i < 4; ++i) {
                float4 t = *reinterpret_cast<const float4*>(&KPs[ty*4 + i][p]);
                pa[i][0] = t.x; pa[i][1] = t.y; pa[i][2] = t.z; pa[i][3] = t.w;
            }
            #pragma unroll
            for (int m = 0; m < 4; ++m) {
                float4 t = *reinterpret_cast<const float4*>(&Vs[p + m][tx*4]);
                vb[m][0] = t.x; vb[m][1] = t.y; vb[m][2] = t.z; vb[m][3] = t.w;
            }
            #pragma unroll
            for (int i = 0; i < 4; ++i)
                #pragma unroll
                for (int m = 0; m < 4; ++m)
                    #pragma unroll
                    for (int j = 0; j < 4; ++j)
                        o[i][j] = fmaf(pa[i][m], vb[m][j], o[i][j]);
        }
    }

    // epilogue: normalize and write to concat[n][h*64 + c]
    #pragma unroll
    for (int i = 0; i < 4; ++i) {
        float inv = 1.0f / l_run[i];
        float4 t;
        t.x = o[i][0] * inv; t.y = o[i][1] * inv; t.z = o[i][2] * inv; t.w = o[i][3] * inv;
        *reinterpret_cast<float4*>(concat + (size_t)(it*64 + ty*4 + i) * DMODEL + h*DHEAD + tx*4) = t;
    }
}

__global__ __launch_bounds__(256) void oproj_kernel(
    const float* __restrict__ concat, const float* __restrict__ wo,
    const float* __restrict__ x, float* __restrict__ res1)
{
    gemm_tile64<0,0,0,1>(concat, DMODEL, wo, DMODEL, res1, DMODEL, DMODEL, 1.0f,
                         nullptr, x, DMODEL, blockIdx.y * 64, blockIdx.x * 64);
}

__global__ __launch_bounds__(256) void ffn1_kernel(
    const float* __restrict__ h1, const float* __restrict__ w1,
    const float* __restrict__ b1, float* __restrict__ ff1)
{
    gemm_tile64<0,1,1,0>(h1, DMODEL, w1, DFF, ff1, DFF, DMODEL, 1.0f,
                         b1, nullptr, 0, blockIdx.y * 64, blockIdx.x * 64);
}

__global__ __launch_bounds__(256) void ffn2_kernel(
    const float* __restrict__ ff1, const float* __restrict__ w2,
    const float* __restrict__ b2, float* __restrict__ ff2)
{
    gemm_tile64<0,1,1,0>(ff1, DFF, w2, DMODEL, ff2, DMODEL, DFF, 1.0f,
                         b2, nullptr, 0, blockIdx.y * 64, blockIdx.x * 64);
}

template<int ADD>
__global__ __launch_bounds__(256) void layernorm_k(
    const float* __restrict__ X, const float* __restrict__ Y,
    const float* __restrict__ g, const float* __restrict__ b,
    float* __restrict__ out)
{
    int row = blockIdx.x, tid = threadIdx.x;
    __shared__ float red[256];
    float vals[4];
    float s = 0.0f;
    #pragma unroll
    for (int i = 0; i < 4; ++i) {
        int c = tid + i * 256;
        float v = X[(size_t)row * DMODEL + c];
        if (ADD) v += Y[(size_t)row * DMODEL + c];
        vals[i] = v; s += v;
    }
    red[tid] = s; __syncthreads();
    for (int st = 128; st > 0; st >>= 1) { if (tid < st) red[tid] += red[tid + st]; __syncthreads(); }
    float mu = red[0] * (1.0f / DMODEL);
    __syncthreads();

    float vs = 0.0f;
    #pragma unroll
    for (int i = 0; i < 4; ++i) { float d = vals[i] - mu; vs += d * d; }
    red[tid] = vs; __syncthreads();
    for (int st = 128; st > 0; st >>= 1) { if (tid < st) red[tid] += red[tid + st]; __syncthreads(); }
    float rstd = rsqrtf(red[0] * (1.0f / DMODEL) + LNEPS);

    #pragma unroll
    for (int i = 0; i < 4; ++i) {
        int c = tid + i * 256;
        out[(size_t)row * DMODEL + c] = (vals[i] - mu) * rstd * g[c] + b[c];
    }
}

extern "C" void kernel_launch(void* const* d_in, const int* in_sizes, int n_in,
                              void* d_out, int out_size, void* d_ws, size_t ws_size,
                              hipStream_t stream)
{
    const float* x    = (const float*)d_in[0];
    const float* wq   = (const float*)d_in[1];
    const float* wk   = (const float*)d_in[2];
    const float* wv   = (const float*)d_in[3];
    const float* wo   = (const float*)d_in[4];
    const float* ln1g = (const float*)d_in[5];
    const float* ln1b = (const float*)d_in[6];
    const float* w1   = (const float*)d_in[7];
    const float* b1   = (const float*)d_in[8];
    const float* w2   = (const float*)d_in[9];
    const float* b2   = (const float*)d_in[10];
    const float* ln2g = (const float*)d_in[11];
    const float* ln2b = (const float*)d_in[12];
    float* out = (float*)d_out;

    char* ws = (char*)d_ws;
    const size_t MB = 1024 * 1024;
    float* q      = (float*)(ws + 0 * MB);   // 8 MiB [H][N][DK]
    float* k      = (float*)(ws + 8 * MB);   // 8 MiB
    float* v      = (float*)(ws + 16 * MB);  // 8 MiB
    float* concat = (float*)(ws + 40 * MB);  // 8 MiB [N][H*DV]
    float* res1   = (float*)(ws + 48 * MB);  // 8 MiB
    float* h1     = (float*)(ws + 56 * MB);  // 8 MiB
    float* ff1    = (float*)(ws + 0 * MB);   // 32 MiB, aliases q/k/v (dead by then)
    float* ff2    = res1;                    // res1 dead after LN1

    dim3 blk(256);

    qkv_kernel<<<dim3(NTOK / 64, NHEAD, 3), blk, 0, stream>>>(x, wq, wk, wv, q, k, v);
    flash_attn<<<dim3(NTOK / 64, NHEAD), blk, 0, stream>>>(q, k, v, concat);
    oproj_kernel<<<dim3(DMODEL / 64, NTOK / 64), blk, 0, stream>>>(concat, wo, x, res1);
    layernorm_k<0><<<dim3(NTOK), blk, 0, stream>>>(res1, nullptr, ln1g, ln1b, h1);
    ffn1_kernel<<<dim3(DFF / 64, NTOK / 64), blk, 0, stream>>>(h1, w1, b1, ff1);
    ffn2_kernel<<<dim3(DMODEL / 64, NTOK / 64), blk, 0, stream>>>(ff1, w2, b2, ff2);
    layernorm_k<1><<<dim3(NTOK), blk, 0, stream>>>(h1, ff2, ln2g, ln2b, out);
}

// Round 3
// 467.066 us; speedup vs baseline: 6.4193x; 2.1578x over previous
//
#include <hip/hip_runtime.h>
#include <math.h>

// TransformerBlock N=2048, D=1024, H=16, DK=DV=64, FF=4096.
// Round 2: all GEMMs -> bf16 MFMA (m97 structure: 128x128 tile, BK=32,
// global_load_lds width-16, 16x16x32 bf16 MFMA, fused epilogues).
// Attention stays fp32 flash (next target).

#define NTOK   2048
#define DMODEL 1024
#define NHEAD  16
#define DHEAD  64
#define DFF    4096
#define LNEPS  1e-5f

typedef unsigned int   u32;
typedef unsigned short u16;
typedef __attribute__((ext_vector_type(8))) short short8;
typedef __attribute__((ext_vector_type(4))) float f32x4;

__device__ __forceinline__ u16 f2b(float f) {
    u32 b = __float_as_uint(f);
    b += 0x7FFFu + ((b >> 16) & 1u);   // RNE
    return (u16)(b >> 16);
}

#define AS1(p) ((const __attribute__((address_space(1))) u32*)(p))
#define AS3(p) ((__attribute__((address_space(3))) u32*)(p))

// ---------------- bf16 MFMA GEMM: C = act(A @ Bt^T + bias + resid) ----------
// A  [M][K] bf16 row-major, Bt [N][K] bf16 row-major (i.e. B transposed).
// 128x128 block tile, BK=32, 256 threads (4 waves, each 64x64 quadrant).
template<int RELU, int BIAS, int RESID, int OUT_BF16>
__global__ __launch_bounds__(256) void mfma_gemm(
    const u16* __restrict__ A, int lda,
    const u16* __restrict__ Bt, int ldbt,
    void* __restrict__ Cp, int ldc, int K,
    const float* __restrict__ bias,
    const float* __restrict__ resid, int ldr)
{
    __shared__ u16 As[128 * 32];   // 8 KB, row-major [row][k]
    __shared__ u16 Bs[128 * 32];   // 8 KB, row-major [col][k]

    const int tid = threadIdx.x;
    const int l = tid & 63, w = tid >> 6;
    const int row0 = blockIdx.y * 128, col0 = blockIdx.x * 128;

    f32x4 acc[4][4];
    #pragma unroll
    for (int m = 0; m < 4; ++m)
        #pragma unroll
        for (int n = 0; n < 4; ++n)
            acc[m][n] = (f32x4){0.f, 0.f, 0.f, 0.f};

    // staging geometry: call c covers tile rows w*32 + c*16 + l/4, kk=(l&3)*8
    const int srow = w * 32 + (l >> 2);
    const int skk  = (l & 3) * 8;
    const u16* Ag = A  + (size_t)(row0 + srow) * lda  + skk;
    const u16* Bg = Bt + (size_t)(col0 + srow) * ldbt + skk;
    char* AsB = (char*)As + w * 2048;
    char* BsB = (char*)Bs + w * 2048;

    const int fr  = l & 15;           // fragment row (A) / col (B)
    const int fk  = (l >> 4) * 8;     // k-group
    const int ar0 = (w >> 1) * 64;    // wave's C quadrant
    const int bc0 = (w & 1) * 64;

    for (int k0 = 0; k0 < K; k0 += 32) {
        __syncthreads();   // previous iter's ds_reads done
        __builtin_amdgcn_global_load_lds(AS1(Ag + k0),                        AS3(AsB),        16, 0, 0);
        __builtin_amdgcn_global_load_lds(AS1(Ag + k0 + (size_t)16 * lda),     AS3(AsB + 1024), 16, 0, 0);
        __builtin_amdgcn_global_load_lds(AS1(Bg + k0),                        AS3(BsB),        16, 0, 0);
        __builtin_amdgcn_global_load_lds(AS1(Bg + k0 + (size_t)16 * ldbt),    AS3(BsB + 1024), 16, 0, 0);
        __syncthreads();   // vmcnt(0) drained by compiler before barrier

        short8 af[4], bfr[4];
        #pragma unroll
        for (int m = 0; m < 4; ++m)
            af[m] = *reinterpret_cast<const short8*>(&As[(ar0 + m * 16 + fr) * 32 + fk]);
        #pragma unroll
        for (int n = 0; n < 4; ++n)
            bfr[n] = *reinterpret_cast<const short8*>(&Bs[(bc0 + n * 16 + fr) * 32 + fk]);
        #pragma unroll
        for (int m = 0; m < 4; ++m)
            #pragma unroll
            for (int n = 0; n < 4; ++n)
                acc[m][n] = __builtin_amdgcn_mfma_f32_16x16x32_bf16(af[m], bfr[n], acc[m][n], 0, 0, 0);
    }

    // epilogue: D lane map col=l&15, row=(l>>4)*4+r  [m89-verified]
    #pragma unroll
    for (int m = 0; m < 4; ++m) {
        #pragma unroll
        for (int n = 0; n < 4; ++n) {
            #pragma unroll
            for (int r = 0; r < 4; ++r) {
                int row = row0 + ar0 + m * 16 + (l >> 4) * 4 + r;
                int col = col0 + bc0 + n * 16 + (l & 15);
                float val = acc[m][n][r];
                if (BIAS)  val += bias[col];
                if (RESID) val += resid[(size_t)row * ldr + col];
                if (RELU)  val = fmaxf(val, 0.0f);
                if (OUT_BF16) ((u16*)Cp)[(size_t)row * ldc + col] = f2b(val);
                else          ((float*)Cp)[(size_t)row * ldc + col] = val;
            }
        }
    }
}

// ---------------- cast / transpose helpers ----------------
__global__ __launch_bounds__(256) void cast_f32_bf16(const float* __restrict__ in,
                                                     u16* __restrict__ out, int n)
{
    int i = (blockIdx.x * 256 + threadIdx.x) * 4;
    if (i + 3 < n) {
        float4 v = *reinterpret_cast<const float4*>(in + i);
        ushort4 o;
        o.x = f2b(v.x); o.y = f2b(v.y); o.z = f2b(v.z); o.w = f2b(v.w);
        *reinterpret_cast<ushort4*>(out + i) = o;
    }
}

// out[c][r] = bf16(in[r][c]) over a 32x32 tile at (blockIdx.y*32, blockIdx.x*32)
__device__ __forceinline__ void transpose_body(const float* __restrict__ in, int ldin,
                                               u16* __restrict__ out, int ldout)
{
    __shared__ float tile[32][33];
    int r0 = blockIdx.y * 32, c0 = blockIdx.x * 32;
    int tx = threadIdx.x & 31, ty = threadIdx.x >> 5;   // 32 x 8
    #pragma unroll
    for (int i = 0; i < 4; ++i) {
        int r = ty + i * 8;
        tile[r][tx] = in[(size_t)(r0 + r) * ldin + c0 + tx];
    }
    __syncthreads();
    #pragma unroll
    for (int i = 0; i < 4; ++i) {
        int rr = ty + i * 8;
        out[(size_t)(c0 + rr) * ldout + r0 + tx] = f2b(tile[tx][rr]);
    }
}

__global__ __launch_bounds__(256) void transpose_cast(const float* __restrict__ in, int ldin,
                                                      u16* __restrict__ out, int ldout)
{
    transpose_body(in, ldin, out, ldout);
}

// wqkvT[(p*1024 + h*64 + kk)][d] = w_p[h][d][kk]; grid (2, 32, 48)
__global__ __launch_bounds__(256) void cast_wqkv(
    const float* __restrict__ wq, const float* __restrict__ wk, const float* __restrict__ wv,
    u16* __restrict__ outT)
{
    int z = blockIdx.z, p = z >> 4, h = z & 15;
    const float* in = (p == 0 ? wq : p == 1 ? wk : wv) + (size_t)h * DMODEL * DHEAD;
    u16* out = outT + (size_t)(p * 1024 + h * 64) * DMODEL;
    transpose_body(in, DHEAD, out, DMODEL);
}

// ---------------- batched fp32 flash attention (qkv fused layout) -----------
// qkv [N][3072]: q at col h*64, k at 1024+h*64, v at 2048+h*64. Output bf16.
__global__ __launch_bounds__(256) void flash_attn(
    const float* __restrict__ qkv, u16* __restrict__ concatb)
{
    const int it = blockIdx.x, h = blockIdx.y;
    const float* qh = qkv + h * DHEAD;
    const float* kh = qkv + DMODEL + h * DHEAD;
    const float* vh = qkv + 2 * DMODEL + h * DHEAD;
    const int LDQ = 3 * DMODEL;

    __shared__ __align__(16) float Qs[64][68];
    __shared__ __align__(16) float KPs[64][68];
    __shared__ __align__(16) float Vs[64][68];

    const int tid = threadIdx.x;
    const int tx = tid & 15, ty = tid >> 4;

    #pragma unroll
    for (int m = 0; m < 4; ++m) {
        int idx = tid + m * 256;
        int r = idx >> 4, c4 = (idx & 15) << 2;
        float4 v4 = *reinterpret_cast<const float4*>(qh + (size_t)(it * 64 + r) * LDQ + c4);
        *reinterpret_cast<float4*>(&Qs[r][c4]) = v4;
    }

    float o[4][4] = {};
    float m_run[4], l_run[4];
    #pragma unroll
    for (int i = 0; i < 4; ++i) { m_run[i] = -INFINITY; l_run[i] = 0.0f; }

    for (int jt = 0; jt <= it; ++jt) {
        __syncthreads();
        #pragma unroll
        for (int m = 0; m < 4; ++m) {
            int idx = tid + m * 256;
            int r = idx >> 4, c4 = (idx & 15) << 2;
            float4 kv = *reinterpret_cast<const float4*>(kh + (size_t)(jt * 64 + r) * LDQ + c4);
            KPs[c4 + 0][r] = kv.x; KPs[c4 + 1][r] = kv.y; KPs[c4 + 2][r] = kv.z; KPs[c4 + 3][r] = kv.w;
            float4 vv = *reinterpret_cast<const float4*>(vh + (size_t)(jt * 64 + r) * LDQ + c4);
            *reinterpret_cast<float4*>(&Vs[r][c4]) = vv;
        }
        __syncthreads();

        float s[4][4] = {};
        #pragma unroll 4
        for (int kk = 0; kk < 64; kk += 4) {
            float qa[4][4], kb[4][4];
            #pragma unroll
            for (int i = 0; i < 4; ++i) {
                float4 t = *reinterpret_cast<const float4*>(&Qs[ty * 4 + i][kk]);
                qa[i][0] = t.x; qa[i][1] = t.y; qa[i][2] = t.z; qa[i][3] = t.w;
            }
            #pragma unroll
            for (int m = 0; m < 4; ++m) {
                float4 t = *reinterpret_cast<const float4*>(&KPs[kk + m][tx * 4]);
                kb[m][0] = t.x; kb[m][1] = t.y; kb[m][2] = t.z; kb[m][3] = t.w;
            }
            #pragma unroll
            for (int i = 0; i < 4; ++i)
                #pragma unroll
                for (int m = 0; m < 4; ++m)
                    #pragma unroll
                    for (int j = 0; j < 4; ++j)
                        s[i][j] = fmaf(qa[i][m], kb[m][j], s[i][j]);
        }

        if (jt == it) {
            #pragma unroll
            for (int i = 0; i < 4; ++i)
                #pragma unroll
                for (int j = 0; j < 4; ++j)
                    if (tx * 4 + j > ty * 4 + i) s[i][j] = -INFINITY;
        }

        float p_[4][4];
        #pragma unroll
        for (int i = 0; i < 4; ++i) {
            float pm = -INFINITY;
            #pragma unroll
            for (int j = 0; j < 4; ++j) pm = fmaxf(pm, s[i][j] * 0.125f);
            pm = fmaxf(pm, __shfl_xor(pm, 1));
            pm = fmaxf(pm, __shfl_xor(pm, 2));
            pm = fmaxf(pm, __shfl_xor(pm, 4));
            pm = fmaxf(pm, __shfl_xor(pm, 8));
            float mnew = fmaxf(m_run[i], pm);
            float corr = __expf(m_run[i] - mnew);
            float rs = 0.0f;
            #pragma unroll
            for (int j = 0; j < 4; ++j) {
                float pv_ = __expf(s[i][j] * 0.125f - mnew);
                p_[i][j] = pv_; rs += pv_;
            }
            rs += __shfl_xor(rs, 1);
            rs += __shfl_xor(rs, 2);
            rs += __shfl_xor(rs, 4);
            rs += __shfl_xor(rs, 8);
            l_run[i] = l_run[i] * corr + rs;
            m_run[i] = mnew;
            #pragma unroll
            for (int j = 0; j < 4; ++j) o[i][j] *= corr;
        }

        __syncthreads();
        #pragma unroll
        for (int i = 0; i < 4; ++i) {
            float4 t; t.x = p_[i][0]; t.y = p_[i][1]; t.z = p_[i][2]; t.w = p_[i][3];
            *reinterpret_cast<float4*>(&KPs[ty * 4 + i][tx * 4]) = t;
        }

        #pragma unroll 4
        for (int p = 0; p < 64; p += 4) {
            float pa[4][4], vb[4][4];
            #pragma unroll
            for (int i = 0; i < 4; ++i) {
                float4 t = *reinterpret_cast<const float4*>(&KPs[ty * 4 + i][p]);
                pa[i][0] = t.x; pa[i][1] = t.y; pa[i][2] = t.z; pa[i][3] = t.w;
            }
            #pragma unroll
            for (int m = 0; m < 4; ++m) {
                float4 t = *reinterpret_cast<const float4*>(&Vs[p + m][tx * 4]);
                vb[m][0] = t.x; vb[m][1] = t.y; vb[m][2] = t.z; vb[m][3] = t.w;
            }
            #pragma unroll
            for (int i = 0; i < 4; ++i)
                #pragma unroll
                for (int m = 0; m < 4; ++m)
                    #pragma unroll
                    for (int j = 0; j < 4; ++j)
                        o[i][j] = fmaf(pa[i][m], vb[m][j], o[i][j]);
        }
    }

    #pragma unroll
    for (int i = 0; i < 4; ++i) {
        float inv = 1.0f / l_run[i];
        ushort4 t;
        t.x = f2b(o[i][0] * inv); t.y = f2b(o[i][1] * inv);
        t.z = f2b(o[i][2] * inv); t.w = f2b(o[i][3] * inv);
        *reinterpret_cast<ushort4*>(concatb + (size_t)(it * 64 + ty * 4 + i) * DMODEL + h * DHEAD + tx * 4) = t;
    }
}

// ---------------- layernorm (optional dual fp32+bf16 output) ----------------
template<int ADD, int DUAL>
__global__ __launch_bounds__(256) void layernorm_k(
    const float* __restrict__ X, const float* __restrict__ Y,
    const float* __restrict__ g, const float* __restrict__ b,
    float* __restrict__ out, u16* __restrict__ outb)
{
    int row = blockIdx.x, tid = threadIdx.x;
    __shared__ float red[256];
    float vals[4];
    float s = 0.0f;
    #pragma unroll
    for (int i = 0; i < 4; ++i) {
        int c = tid + i * 256;
        float v = X[(size_t)row * DMODEL + c];
        if (ADD) v += Y[(size_t)row * DMODEL + c];
        vals[i] = v; s += v;
    }
    red[tid] = s; __syncthreads();
    for (int st = 128; st > 0; st >>= 1) { if (tid < st) red[tid] += red[tid + st]; __syncthreads(); }
    float mu = red[0] * (1.0f / DMODEL);
    __syncthreads();

    float vs = 0.0f;
    #pragma unroll
    for (int i = 0; i < 4; ++i) { float d = vals[i] - mu; vs += d * d; }
    red[tid] = vs; __syncthreads();
    for (int st = 128; st > 0; st >>= 1) { if (tid < st) red[tid] += red[tid + st]; __syncthreads(); }
    float rstd = rsqrtf(red[0] * (1.0f / DMODEL) + LNEPS);

    #pragma unroll
    for (int i = 0; i < 4; ++i) {
        int c = tid + i * 256;
        float r = (vals[i] - mu) * rstd * g[c] + b[c];
        out[(size_t)row * DMODEL + c] = r;
        if (DUAL) outb[(size_t)row * DMODEL + c] = f2b(r);
    }
}

// ---------------- launch ----------------
extern "C" void kernel_launch(void* const* d_in, const int* in_sizes, int n_in,
                              void* d_out, int out_size, void* d_ws, size_t ws_size,
                              hipStream_t stream)
{
    const float* x    = (const float*)d_in[0];
    const float* wq   = (const float*)d_in[1];
    const float* wk   = (const float*)d_in[2];
    const float* wv   = (const float*)d_in[3];
    const float* wo   = (const float*)d_in[4];
    const float* ln1g = (const float*)d_in[5];
    const float* ln1b = (const float*)d_in[6];
    const float* w1   = (const float*)d_in[7];
    const float* b1   = (const float*)d_in[8];
    const float* w2   = (const float*)d_in[9];
    const float* b2   = (const float*)d_in[10];
    const float* ln2g = (const float*)d_in[11];
    const float* ln2b = (const float*)d_in[12];
    float* out = (float*)d_out;

    char* ws = (char*)d_ws;
    const size_t MB = 1024 * 1024;
    u16*   xb      = (u16*)  (ws + 0 * MB);   // 4 MB
    u16*   wqkvT   = (u16*)  (ws + 4 * MB);   // 6 MB  [3072][1024]
    u16*   woT     = (u16*)  (ws + 10 * MB);  // 2 MB  [1024][1024]
    u16*   w1T     = (u16*)  (ws + 12 * MB);  // 8 MB  [4096][1024]
    u16*   w2T     = (u16*)  (ws + 20 * MB);  // 8 MB  [1024][4096]
    float* qkv     = (float*)(ws + 28 * MB);  // 24 MB [2048][3072]
    u16*   concatb = (u16*)  (ws + 0 * MB);   // 4 MB (xb dead)
    float* res1    = (float*)(ws + 28 * MB);  // 8 MB (qkv dead)
    float* h1      = (float*)(ws + 36 * MB);  // 8 MB
    u16*   h1b     = (u16*)  (ws + 44 * MB);  // 4 MB
    u16*   ff1b    = (u16*)  (ws + 48 * MB);  // 16 MB [2048][4096]
    float* ff2     = (float*)(ws + 28 * MB);  // 8 MB (res1 dead)

    dim3 blk(256);

    cast_f32_bf16<<<dim3(NTOK * DMODEL / 1024), blk, 0, stream>>>(x, xb, NTOK * DMODEL);
    cast_wqkv<<<dim3(2, 32, 48), blk, 0, stream>>>(wq, wk, wv, wqkvT);
    transpose_cast<<<dim3(32, 32),  blk, 0, stream>>>(wo, DMODEL, woT, DMODEL);
    transpose_cast<<<dim3(128, 32), blk, 0, stream>>>(w1, DFF, w1T, DMODEL);
    transpose_cast<<<dim3(32, 128), blk, 0, stream>>>(w2, DMODEL, w2T, DFF);

    // qkv = xb @ wqkvT^T   [2048][3072] fp32
    mfma_gemm<0,0,0,0><<<dim3(24, 16), blk, 0, stream>>>(xb, DMODEL, wqkvT, DMODEL,
                                                         qkv, 3 * DMODEL, DMODEL,
                                                         nullptr, nullptr, 0);
    flash_attn<<<dim3(NTOK / 64, NHEAD), blk, 0, stream>>>(qkv, concatb);
    // res1 = concatb @ woT^T + x   fp32
    mfma_gemm<0,0,1,0><<<dim3(8, 16), blk, 0, stream>>>(concatb, DMODEL, woT, DMODEL,
                                                        res1, DMODEL, DMODEL,
                                                        nullptr, x, DMODEL);
    layernorm_k<0,1><<<dim3(NTOK), blk, 0, stream>>>(res1, nullptr, ln1g, ln1b, h1, h1b);
    // ff1 = relu(h1b @ w1T^T + b1) -> bf16
    mfma_gemm<1,1,0,1><<<dim3(32, 16), blk, 0, stream>>>(h1b, DMODEL, w1T, DMODEL,
                                                         ff1b, DFF, DMODEL,
                                                         b1, nullptr, 0);
    // ff2 = relu(ff1b @ w2T^T + b2) fp32
    mfma_gemm<1,1,0,0><<<dim3(8, 16), blk, 0, stream>>>(ff1b, DFF, w2T, DFF,
                                                        ff2, DMODEL, DFF,
                                                        b2, nullptr, 0);
    layernorm_k<1,0><<<dim3(NTOK), blk, 0, stream>>>(h1, ff2, ln2g, ln2b, out, nullptr);
}

// Round 4
// 282.889 us; speedup vs baseline: 10.5986x; 1.6511x over previous
//
#include <hip/hip_runtime.h>
#include <math.h>

// TransformerBlock N=2048, D=1024, H=16, DK=DV=64, FF=4096.
// Round 4: MFMA flash attention (bf16 QK^T + PV on matrix cores),
// qkv GEMM emits bf16 directly. GEMMs unchanged (m97 structure).

#define NTOK   2048
#define DMODEL 1024
#define NHEAD  16
#define DHEAD  64
#define DFF    4096
#define LNEPS  1e-5f

typedef unsigned int   u32;
typedef unsigned short u16;
typedef __attribute__((ext_vector_type(8))) short short8;
typedef __attribute__((ext_vector_type(4))) float f32x4;

__device__ __forceinline__ u16 f2b(float f) {
    u32 b = __float_as_uint(f);
    b += 0x7FFFu + ((b >> 16) & 1u);   // RNE
    return (u16)(b >> 16);
}

#define AS1(p) ((const __attribute__((address_space(1))) u32*)(p))
#define AS3(p) ((__attribute__((address_space(3))) u32*)(p))

// ---------------- bf16 MFMA GEMM: C = act(A @ Bt^T + bias + resid) ----------
template<int RELU, int BIAS, int RESID, int OUT_BF16>
__global__ __launch_bounds__(256) void mfma_gemm(
    const u16* __restrict__ A, int lda,
    const u16* __restrict__ Bt, int ldbt,
    void* __restrict__ Cp, int ldc, int K,
    const float* __restrict__ bias,
    const float* __restrict__ resid, int ldr)
{
    __shared__ u16 As[128 * 32];
    __shared__ u16 Bs[128 * 32];

    const int tid = threadIdx.x;
    const int l = tid & 63, w = tid >> 6;
    const int row0 = blockIdx.y * 128, col0 = blockIdx.x * 128;

    f32x4 acc[4][4];
    #pragma unroll
    for (int m = 0; m < 4; ++m)
        #pragma unroll
        for (int n = 0; n < 4; ++n)
            acc[m][n] = (f32x4){0.f, 0.f, 0.f, 0.f};

    const int srow = w * 32 + (l >> 2);
    const int skk  = (l & 3) * 8;
    const u16* Ag = A  + (size_t)(row0 + srow) * lda  + skk;
    const u16* Bg = Bt + (size_t)(col0 + srow) * ldbt + skk;
    char* AsB = (char*)As + w * 2048;
    char* BsB = (char*)Bs + w * 2048;

    const int fr  = l & 15;
    const int fk  = (l >> 4) * 8;
    const int ar0 = (w >> 1) * 64;
    const int bc0 = (w & 1) * 64;

    for (int k0 = 0; k0 < K; k0 += 32) {
        __syncthreads();
        __builtin_amdgcn_global_load_lds(AS1(Ag + k0),                     AS3(AsB),        16, 0, 0);
        __builtin_amdgcn_global_load_lds(AS1(Ag + k0 + (size_t)16 * lda),  AS3(AsB + 1024), 16, 0, 0);
        __builtin_amdgcn_global_load_lds(AS1(Bg + k0),                     AS3(BsB),        16, 0, 0);
        __builtin_amdgcn_global_load_lds(AS1(Bg + k0 + (size_t)16 * ldbt), AS3(BsB + 1024), 16, 0, 0);
        __syncthreads();

        short8 af[4], bfr[4];
        #pragma unroll
        for (int m = 0; m < 4; ++m)
            af[m] = *reinterpret_cast<const short8*>(&As[(ar0 + m * 16 + fr) * 32 + fk]);
        #pragma unroll
        for (int n = 0; n < 4; ++n)
            bfr[n] = *reinterpret_cast<const short8*>(&Bs[(bc0 + n * 16 + fr) * 32 + fk]);
        #pragma unroll
        for (int m = 0; m < 4; ++m)
            #pragma unroll
            for (int n = 0; n < 4; ++n)
                acc[m][n] = __builtin_amdgcn_mfma_f32_16x16x32_bf16(af[m], bfr[n], acc[m][n], 0, 0, 0);
    }

    #pragma unroll
    for (int m = 0; m < 4; ++m) {
        #pragma unroll
        for (int n = 0; n < 4; ++n) {
            #pragma unroll
            for (int r = 0; r < 4; ++r) {
                int row = row0 + ar0 + m * 16 + (l >> 4) * 4 + r;
                int col = col0 + bc0 + n * 16 + (l & 15);
                float val = acc[m][n][r];
                if (BIAS)  val += bias[col];
                if (RESID) val += resid[(size_t)row * ldr + col];
                if (RELU)  val = fmaxf(val, 0.0f);
                if (OUT_BF16) ((u16*)Cp)[(size_t)row * ldc + col] = f2b(val);
                else          ((float*)Cp)[(size_t)row * ldc + col] = val;
            }
        }
    }
}

// ---------------- cast / transpose helpers ----------------
__global__ __launch_bounds__(256) void cast_f32_bf16(const float* __restrict__ in,
                                                     u16* __restrict__ out, int n)
{
    int i = (blockIdx.x * 256 + threadIdx.x) * 4;
    if (i + 3 < n) {
        float4 v = *reinterpret_cast<const float4*>(in + i);
        ushort4 o;
        o.x = f2b(v.x); o.y = f2b(v.y); o.z = f2b(v.z); o.w = f2b(v.w);
        *reinterpret_cast<ushort4*>(out + i) = o;
    }
}

__device__ __forceinline__ void transpose_body(const float* __restrict__ in, int ldin,
                                               u16* __restrict__ out, int ldout)
{
    __shared__ float tile[32][33];
    int r0 = blockIdx.y * 32, c0 = blockIdx.x * 32;
    int tx = threadIdx.x & 31, ty = threadIdx.x >> 5;
    #pragma unroll
    for (int i = 0; i < 4; ++i) {
        int r = ty + i * 8;
        tile[r][tx] = in[(size_t)(r0 + r) * ldin + c0 + tx];
    }
    __syncthreads();
    #pragma unroll
    for (int i = 0; i < 4; ++i) {
        int rr = ty + i * 8;
        out[(size_t)(c0 + rr) * ldout + r0 + tx] = f2b(tile[tx][rr]);
    }
}

__global__ __launch_bounds__(256) void transpose_cast(const float* __restrict__ in, int ldin,
                                                      u16* __restrict__ out, int ldout)
{
    transpose_body(in, ldin, out, ldout);
}

__global__ __launch_bounds__(256) void cast_wqkv(
    const float* __restrict__ wq, const float* __restrict__ wk, const float* __restrict__ wv,
    u16* __restrict__ outT)
{
    int z = blockIdx.z, p = z >> 4, h = z & 15;
    const float* in = (p == 0 ? wq : p == 1 ? wk : wv) + (size_t)h * DMODEL * DHEAD;
    u16* out = outT + (size_t)(p * 1024 + h * 64) * DMODEL;
    transpose_body(in, DHEAD, out, DMODEL);
}

// ---------------- MFMA flash attention ----------------
// qkvb [N][3072] bf16: q at h*64, k at 1024+h*64, v at 2048+h*64.
// grid (N/64, H), 256 threads = 4 waves; wave w owns q-rows it*64+w*16..+15.
__global__ __launch_bounds__(256) void flash_attn_mfma(
    const u16* __restrict__ qkvb, u16* __restrict__ concatb)
{
    const int it = blockIdx.x, h = blockIdx.y;
    const u16* qh = qkvb + h * DHEAD;
    const u16* kh = qkvb + DMODEL + h * DHEAD;
    const u16* vh = qkvb + 2 * DMODEL + h * DHEAD;
    const int LDQ = 3 * DMODEL;

    __shared__ u16 Ks[64][72];       // K rows (padded: frag reads 2-way max)
    __shared__ u16 Vt[64][72];       // V transposed [dv][kv]
    __shared__ u16 Ps[4][16][72];    // per-wave P tile (bf16)

    const int tid = threadIdx.x;
    const int l = tid & 63, w = tid >> 6;
    const int fr = l & 15, fg = l >> 4;       // fragment row / k-group

    // Q fragments: lane holds Q[row=fr][k=fg*8..+7], 2 k-steps
    short8 qf[2];
    {
        const u16* qp = qh + (size_t)(it * 64 + w * 16 + fr) * LDQ + fg * 8;
        qf[0] = *reinterpret_cast<const short8*>(qp);
        qf[1] = *reinterpret_cast<const short8*>(qp + 32);
    }

    f32x4 o[4];
    #pragma unroll
    for (int n = 0; n < 4; ++n) o[n] = (f32x4){0.f, 0.f, 0.f, 0.f};
    float m_run[4], l_run[4];
    #pragma unroll
    for (int r = 0; r < 4; ++r) { m_run[r] = -INFINITY; l_run[r] = 0.0f; }

    for (int jt = 0; jt <= it; ++jt) {
        __syncthreads();   // previous tile's K/V readers done
        {   // stage K rows: thread -> row tid>>2, 16 cols at (tid&3)*16
            int r = tid >> 2, c = (tid & 3) * 16;
            const u16* kg = kh + (size_t)(jt * 64 + r) * LDQ + c;
            *reinterpret_cast<short8*>(&Ks[r][c])     = *reinterpret_cast<const short8*>(kg);
            *reinterpret_cast<short8*>(&Ks[r][c + 8]) = *reinterpret_cast<const short8*>(kg + 8);
        }
        {   // stage V transposed: row-pair 2p/2p+1, 8 dv cols at (tid&7)*8
            int p = tid >> 3, c = (tid & 7) * 8;
            const u16* vg = vh + (size_t)(jt * 64 + 2 * p) * LDQ + c;
            short8 v0 = *reinterpret_cast<const short8*>(vg);
            short8 v1 = *reinterpret_cast<const short8*>(vg + LDQ);
            #pragma unroll
            for (int i = 0; i < 8; ++i) {
                u32 word = (u32)(u16)v0[i] | ((u32)(u16)v1[i] << 16);
                *reinterpret_cast<u32*>(&Vt[c + i][2 * p]) = word;
            }
        }
        __syncthreads();

        // S = Q @ K^T : 4 col-frags x 2 k-steps
        f32x4 s[4];
        #pragma unroll
        for (int n = 0; n < 4; ++n) s[n] = (f32x4){0.f, 0.f, 0.f, 0.f};
        #pragma unroll
        for (int n = 0; n < 4; ++n) {
            #pragma unroll
            for (int ks = 0; ks < 2; ++ks) {
                short8 bfK = *reinterpret_cast<const short8*>(&Ks[n * 16 + fr][ks * 32 + fg * 8]);
                s[n] = __builtin_amdgcn_mfma_f32_16x16x32_bf16(qf[ks], bfK, s[n], 0, 0, 0);
            }
        }

        // online softmax per C-layout row (row = fg*4 + r)
        const bool diag = (jt == it);
        #pragma unroll
        for (int r = 0; r < 4; ++r) {
            int qrow = w * 16 + fg * 4 + r;            // within tile; global adds it*64
            float sv[4];
            float pm = -INFINITY;
            #pragma unroll
            for (int n = 0; n < 4; ++n) {
                float vsc = s[n][r] * 0.125f;
                if (diag && (n * 16 + fr) > qrow) vsc = -INFINITY;
                sv[n] = vsc;
                pm = fmaxf(pm, vsc);
            }
            pm = fmaxf(pm, __shfl_xor(pm, 1));
            pm = fmaxf(pm, __shfl_xor(pm, 2));
            pm = fmaxf(pm, __shfl_xor(pm, 4));
            pm = fmaxf(pm, __shfl_xor(pm, 8));
            float mnew = fmaxf(m_run[r], pm);
            float corr = __expf(m_run[r] - mnew);
            float rs = 0.0f;
            #pragma unroll
            for (int n = 0; n < 4; ++n) {
                float pv = __expf(sv[n] - mnew);
                rs += pv;
                Ps[w][fg * 4 + r][n * 16 + fr] = f2b(pv);
            }
            rs += __shfl_xor(rs, 1);
            rs += __shfl_xor(rs, 2);
            rs += __shfl_xor(rs, 4);
            rs += __shfl_xor(rs, 8);
            l_run[r] = l_run[r] * corr + rs;
            m_run[r] = mnew;
            #pragma unroll
            for (int n = 0; n < 4; ++n) o[n][r] *= corr;
        }

        // O += P @ V : A-frag from Ps (row fr, k contiguous), B-frag from Vt
        #pragma unroll
        for (int ks = 0; ks < 2; ++ks) {
            short8 pa = *reinterpret_cast<const short8*>(&Ps[w][fr][ks * 32 + fg * 8]);
            #pragma unroll
            for (int n = 0; n < 4; ++n) {
                short8 vb = *reinterpret_cast<const short8*>(&Vt[n * 16 + fr][ks * 32 + fg * 8]);
                o[n] = __builtin_amdgcn_mfma_f32_16x16x32_bf16(pa, vb, o[n], 0, 0, 0);
            }
        }
    }

    // epilogue: normalize, write concat[q][h*64+dv] bf16
    #pragma unroll
    for (int r = 0; r < 4; ++r) {
        float inv = 1.0f / l_run[r];
        int qrow = it * 64 + w * 16 + fg * 4 + r;
        #pragma unroll
        for (int n = 0; n < 4; ++n)
            concatb[(size_t)qrow * DMODEL + h * DHEAD + n * 16 + fr] = f2b(o[n][r] * inv);
    }
}

// ---------------- layernorm ----------------
template<int ADD, int DUAL>
__global__ __launch_bounds__(256) void layernorm_k(
    const float* __restrict__ X, const float* __restrict__ Y,
    const float* __restrict__ g, const float* __restrict__ b,
    float* __restrict__ out, u16* __restrict__ outb)
{
    int row = blockIdx.x, tid = threadIdx.x;
    __shared__ float red[256];
    float vals[4];
    float s = 0.0f;
    #pragma unroll
    for (int i = 0; i < 4; ++i) {
        int c = tid + i * 256;
        float v = X[(size_t)row * DMODEL + c];
        if (ADD) v += Y[(size_t)row * DMODEL + c];
        vals[i] = v; s += v;
    }
    red[tid] = s; __syncthreads();
    for (int st = 128; st > 0; st >>= 1) { if (tid < st) red[tid] += red[tid + st]; __syncthreads(); }
    float mu = red[0] * (1.0f / DMODEL);
    __syncthreads();

    float vs = 0.0f;
    #pragma unroll
    for (int i = 0; i < 4; ++i) { float d = vals[i] - mu; vs += d * d; }
    red[tid] = vs; __syncthreads();
    for (int st = 128; st > 0; st >>= 1) { if (tid < st) red[tid] += red[tid + st]; __syncthreads(); }
    float rstd = rsqrtf(red[0] * (1.0f / DMODEL) + LNEPS);

    #pragma unroll
    for (int i = 0; i < 4; ++i) {
        int c = tid + i * 256;
        float r = (vals[i] - mu) * rstd * g[c] + b[c];
        out[(size_t)row * DMODEL + c] = r;
        if (DUAL) outb[(size_t)row * DMODEL + c] = f2b(r);
    }
}

// ---------------- launch ----------------
extern "C" void kernel_launch(void* const* d_in, const int* in_sizes, int n_in,
                              void* d_out, int out_size, void* d_ws, size_t ws_size,
                              hipStream_t stream)
{
    const float* x    = (const float*)d_in[0];
    const float* wq   = (const float*)d_in[1];
    const float* wk   = (const float*)d_in[2];
    const float* wv   = (const float*)d_in[3];
    const float* wo   = (const float*)d_in[4];
    const float* ln1g = (const float*)d_in[5];
    const float* ln1b = (const float*)d_in[6];
    const float* w1   = (const float*)d_in[7];
    const float* b1   = (const float*)d_in[8];
    const float* w2   = (const float*)d_in[9];
    const float* b2   = (const float*)d_in[10];
    const float* ln2g = (const float*)d_in[11];
    const float* ln2b = (const float*)d_in[12];
    float* out = (float*)d_out;

    char* ws = (char*)d_ws;
    const size_t MB = 1024 * 1024;
    u16*   wqkvT   = (u16*)  (ws + 0 * MB);   // 6 MB  [3072][1024]
    u16*   woT     = (u16*)  (ws + 6 * MB);   // 2 MB
    u16*   w1T     = (u16*)  (ws + 8 * MB);   // 8 MB
    u16*   w2T     = (u16*)  (ws + 16 * MB);  // 8 MB
    u16*   xb      = (u16*)  (ws + 24 * MB);  // 4 MB
    u16*   qkvb    = (u16*)  (ws + 28 * MB);  // 12 MB [2048][3072] bf16
    u16*   concatb = (u16*)  (ws + 24 * MB);  // 4 MB (xb dead after qkv GEMM)
    float* res1    = (float*)(ws + 40 * MB);  // 8 MB
    float* h1      = (float*)(ws + 48 * MB);  // 8 MB
    u16*   h1b     = (u16*)  (ws + 28 * MB);  // 4 MB (qkvb dead after flash)
    u16*   ff1b    = (u16*)  (ws + 32 * MB);  // 16 MB (qkvb tail + res1 dead after LN1)
    float* ff2     = (float*)(ws + 56 * MB);  // 8 MB

    dim3 blk(256);

    cast_f32_bf16<<<dim3(NTOK * DMODEL / 1024), blk, 0, stream>>>(x, xb, NTOK * DMODEL);
    cast_wqkv<<<dim3(2, 32, 48), blk, 0, stream>>>(wq, wk, wv, wqkvT);
    transpose_cast<<<dim3(32, 32),  blk, 0, stream>>>(wo, DMODEL, woT, DMODEL);
    transpose_cast<<<dim3(128, 32), blk, 0, stream>>>(w1, DFF, w1T, DMODEL);
    transpose_cast<<<dim3(32, 128), blk, 0, stream>>>(w2, DMODEL, w2T, DFF);

    // qkvb = bf16(xb @ wqkvT^T)
    mfma_gemm<0,0,0,1><<<dim3(24, 16), blk, 0, stream>>>(xb, DMODEL, wqkvT, DMODEL,
                                                         qkvb, 3 * DMODEL, DMODEL,
                                                         nullptr, nullptr, 0);
    flash_attn_mfma<<<dim3(NTOK / 64, NHEAD), blk, 0, stream>>>(qkvb, concatb);
    // res1 = concatb @ woT^T + x
    mfma_gemm<0,0,1,0><<<dim3(8, 16), blk, 0, stream>>>(concatb, DMODEL, woT, DMODEL,
                                                        res1, DMODEL, DMODEL,
                                                        nullptr, x, DMODEL);
    layernorm_k<0,1><<<dim3(NTOK), blk, 0, stream>>>(res1, nullptr, ln1g, ln1b, h1, h1b);
    mfma_gemm<1,1,0,1><<<dim3(32, 16), blk, 0, stream>>>(h1b, DMODEL, w1T, DMODEL,
                                                         ff1b, DFF, DMODEL,
                                                         b1, nullptr, 0);
    mfma_gemm<1,1,0,0><<<dim3(8, 16), blk, 0, stream>>>(ff1b, DFF, w2T, DFF,
                                                        ff2, DMODEL, DFF,
                                                        b2, nullptr, 0);
    layernorm_k<1,0><<<dim3(NTOK), blk, 0, stream>>>(h1, ff2, ln2g, ln2b, out, nullptr);
}

// Round 5
// 221.259 us; speedup vs baseline: 13.5508x; 1.2785x over previous
//
#include <hip/hip_runtime.h>
#include <math.h>

// TransformerBlock N=2048, D=1024, H=16, DK=DV=64, FF=4096.
// Round 5: split-K for under-parallelized GEMMs (ffn2 x4, oproj x2; partial
// reduce fused into the following LayerNorm) + 2-phase double-buffered LDS
// pipeline in all MFMA GEMMs (stage next tile during compute).

#define NTOK   2048
#define DMODEL 1024
#define NHEAD  16
#define DHEAD  64
#define DFF    4096
#define LNEPS  1e-5f

typedef unsigned int   u32;
typedef unsigned short u16;
typedef __attribute__((ext_vector_type(8))) short short8;
typedef __attribute__((ext_vector_type(4))) float f32x4;

__device__ __forceinline__ u16 f2b(float f) {
    u32 b = __float_as_uint(f);
    b += 0x7FFFu + ((b >> 16) & 1u);   // RNE
    return (u16)(b >> 16);
}

#define AS1(p) ((const __attribute__((address_space(1))) u32*)(p))
#define AS3(p) ((__attribute__((address_space(3))) u32*)(p))

// ---------------- bf16 MFMA GEMM, 128x128 tile, BK=32, 2-phase dbuf --------
// A [M][K] bf16 row-major, Bt [N][K] bf16 row-major.
// SPLITK>1: blockIdx.z picks K-chunk of size Kc; writes fp32 partial to
// (float*)Cp + z*pstride, no epilogue. Else: fused bias/resid/relu epilogue.
template<int RELU, int BIAS, int RESID, int OUT_BF16, int SPLITK>
__global__ __launch_bounds__(256) void mfma_gemm(
    const u16* __restrict__ A, int lda,
    const u16* __restrict__ Bt, int ldbt,
    void* __restrict__ Cp, int ldc, int Kc,
    const float* __restrict__ bias,
    const float* __restrict__ resid, int ldr,
    size_t pstride)
{
    __shared__ u16 As[2][128 * 32];   // 2 x 8 KB
    __shared__ u16 Bs[2][128 * 32];

    const int tid = threadIdx.x;
    const int l = tid & 63, w = tid >> 6;
    const int row0 = blockIdx.y * 128, col0 = blockIdx.x * 128;
    const int kbase = (SPLITK > 1) ? blockIdx.z * Kc : 0;

    f32x4 acc[4][4];
    #pragma unroll
    for (int m = 0; m < 4; ++m)
        #pragma unroll
        for (int n = 0; n < 4; ++n)
            acc[m][n] = (f32x4){0.f, 0.f, 0.f, 0.f};

    const int srow = w * 32 + (l >> 2);
    const int skk  = (l & 3) * 8;
    const u16* Ag = A  + (size_t)(row0 + srow) * lda  + kbase + skk;
    const u16* Bg = Bt + (size_t)(col0 + srow) * ldbt + kbase + skk;

    const int fr  = l & 15;
    const int fk  = (l >> 4) * 8;
    const int ar0 = (w >> 1) * 64;
    const int bc0 = (w & 1) * 64;

    auto STAGE = [&](int buf, int k0) {
        char* AsB = (char*)&As[buf][0] + w * 2048;
        char* BsB = (char*)&Bs[buf][0] + w * 2048;
        __builtin_amdgcn_global_load_lds(AS1(Ag + k0),                     AS3(AsB),        16, 0, 0);
        __builtin_amdgcn_global_load_lds(AS1(Ag + k0 + (size_t)16 * lda),  AS3(AsB + 1024), 16, 0, 0);
        __builtin_amdgcn_global_load_lds(AS1(Bg + k0),                     AS3(BsB),        16, 0, 0);
        __builtin_amdgcn_global_load_lds(AS1(Bg + k0 + (size_t)16 * ldbt), AS3(BsB + 1024), 16, 0, 0);
    };

    STAGE(0, 0);
    int cur = 0;
    for (int k0 = 0; k0 < Kc; k0 += 32) {
        __syncthreads();                       // drains vmcnt(0): buf[cur] ready
        if (k0 + 32 < Kc) STAGE(cur ^ 1, k0 + 32);   // overlap with compute

        short8 af[4], bfr[4];
        #pragma unroll
        for (int m = 0; m < 4; ++m)
            af[m] = *reinterpret_cast<const short8*>(&As[cur][(ar0 + m * 16 + fr) * 32 + fk]);
        #pragma unroll
        for (int n = 0; n < 4; ++n)
            bfr[n] = *reinterpret_cast<const short8*>(&Bs[cur][(bc0 + n * 16 + fr) * 32 + fk]);
        #pragma unroll
        for (int m = 0; m < 4; ++m)
            #pragma unroll
            for (int n = 0; n < 4; ++n)
                acc[m][n] = __builtin_amdgcn_mfma_f32_16x16x32_bf16(af[m], bfr[n], acc[m][n], 0, 0, 0);
        cur ^= 1;
    }

    if (SPLITK > 1) {
        float* Pp = (float*)Cp + blockIdx.z * pstride;
        #pragma unroll
        for (int m = 0; m < 4; ++m)
            #pragma unroll
            for (int n = 0; n < 4; ++n)
                #pragma unroll
                for (int r = 0; r < 4; ++r) {
                    int row = row0 + ar0 + m * 16 + (l >> 4) * 4 + r;
                    int col = col0 + bc0 + n * 16 + (l & 15);
                    Pp[(size_t)row * ldc + col] = acc[m][n][r];
                }
        return;
    }

    #pragma unroll
    for (int m = 0; m < 4; ++m) {
        #pragma unroll
        for (int n = 0; n < 4; ++n) {
            #pragma unroll
            for (int r = 0; r < 4; ++r) {
                int row = row0 + ar0 + m * 16 + (l >> 4) * 4 + r;
                int col = col0 + bc0 + n * 16 + (l & 15);
                float val = acc[m][n][r];
                if (BIAS)  val += bias[col];
                if (RESID) val += resid[(size_t)row * ldr + col];
                if (RELU)  val = fmaxf(val, 0.0f);
                if (OUT_BF16) ((u16*)Cp)[(size_t)row * ldc + col] = f2b(val);
                else          ((float*)Cp)[(size_t)row * ldc + col] = val;
            }
        }
    }
}

// ---------------- cast / transpose helpers ----------------
__global__ __launch_bounds__(256) void cast_f32_bf16(const float* __restrict__ in,
                                                     u16* __restrict__ out, int n)
{
    int i = (blockIdx.x * 256 + threadIdx.x) * 4;
    if (i + 3 < n) {
        float4 v = *reinterpret_cast<const float4*>(in + i);
        ushort4 o;
        o.x = f2b(v.x); o.y = f2b(v.y); o.z = f2b(v.z); o.w = f2b(v.w);
        *reinterpret_cast<ushort4*>(out + i) = o;
    }
}

__device__ __forceinline__ void transpose_body(const float* __restrict__ in, int ldin,
                                               u16* __restrict__ out, int ldout)
{
    __shared__ float tile[32][33];
    int r0 = blockIdx.y * 32, c0 = blockIdx.x * 32;
    int tx = threadIdx.x & 31, ty = threadIdx.x >> 5;
    #pragma unroll
    for (int i = 0; i < 4; ++i) {
        int r = ty + i * 8;
        tile[r][tx] = in[(size_t)(r0 + r) * ldin + c0 + tx];
    }
    __syncthreads();
    #pragma unroll
    for (int i = 0; i < 4; ++i) {
        int rr = ty + i * 8;
        out[(size_t)(c0 + rr) * ldout + r0 + tx] = f2b(tile[tx][rr]);
    }
}

__global__ __launch_bounds__(256) void transpose_cast(const float* __restrict__ in, int ldin,
                                                      u16* __restrict__ out, int ldout)
{
    transpose_body(in, ldin, out, ldout);
}

__global__ __launch_bounds__(256) void cast_wqkv(
    const float* __restrict__ wq, const float* __restrict__ wk, const float* __restrict__ wv,
    u16* __restrict__ outT)
{
    int z = blockIdx.z, p = z >> 4, h = z & 15;
    const float* in = (p == 0 ? wq : p == 1 ? wk : wv) + (size_t)h * DMODEL * DHEAD;
    u16* out = outT + (size_t)(p * 1024 + h * 64) * DMODEL;
    transpose_body(in, DHEAD, out, DMODEL);
}

// ---------------- MFMA flash attention (unchanged) ----------------
__global__ __launch_bounds__(256) void flash_attn_mfma(
    const u16* __restrict__ qkvb, u16* __restrict__ concatb)
{
    const int it = blockIdx.x, h = blockIdx.y;
    const u16* qh = qkvb + h * DHEAD;
    const u16* kh = qkvb + DMODEL + h * DHEAD;
    const u16* vh = qkvb + 2 * DMODEL + h * DHEAD;
    const int LDQ = 3 * DMODEL;

    __shared__ u16 Ks[64][72];
    __shared__ u16 Vt[64][72];
    __shared__ u16 Ps[4][16][72];

    const int tid = threadIdx.x;
    const int l = tid & 63, w = tid >> 6;
    const int fr = l & 15, fg = l >> 4;

    short8 qf[2];
    {
        const u16* qp = qh + (size_t)(it * 64 + w * 16 + fr) * LDQ + fg * 8;
        qf[0] = *reinterpret_cast<const short8*>(qp);
        qf[1] = *reinterpret_cast<const short8*>(qp + 32);
    }

    f32x4 o[4];
    #pragma unroll
    for (int n = 0; n < 4; ++n) o[n] = (f32x4){0.f, 0.f, 0.f, 0.f};
    float m_run[4], l_run[4];
    #pragma unroll
    for (int r = 0; r < 4; ++r) { m_run[r] = -INFINITY; l_run[r] = 0.0f; }

    for (int jt = 0; jt <= it; ++jt) {
        __syncthreads();
        {
            int r = tid >> 2, c = (tid & 3) * 16;
            const u16* kg = kh + (size_t)(jt * 64 + r) * LDQ + c;
            *reinterpret_cast<short8*>(&Ks[r][c])     = *reinterpret_cast<const short8*>(kg);
            *reinterpret_cast<short8*>(&Ks[r][c + 8]) = *reinterpret_cast<const short8*>(kg + 8);
        }
        {
            int p = tid >> 3, c = (tid & 7) * 8;
            const u16* vg = vh + (size_t)(jt * 64 + 2 * p) * LDQ + c;
            short8 v0 = *reinterpret_cast<const short8*>(vg);
            short8 v1 = *reinterpret_cast<const short8*>(vg + LDQ);
            #pragma unroll
            for (int i = 0; i < 8; ++i) {
                u32 word = (u32)(u16)v0[i] | ((u32)(u16)v1[i] << 16);
                *reinterpret_cast<u32*>(&Vt[c + i][2 * p]) = word;
            }
        }
        __syncthreads();

        f32x4 s[4];
        #pragma unroll
        for (int n = 0; n < 4; ++n) s[n] = (f32x4){0.f, 0.f, 0.f, 0.f};
        #pragma unroll
        for (int n = 0; n < 4; ++n) {
            #pragma unroll
            for (int ks = 0; ks < 2; ++ks) {
                short8 bfK = *reinterpret_cast<const short8*>(&Ks[n * 16 + fr][ks * 32 + fg * 8]);
                s[n] = __builtin_amdgcn_mfma_f32_16x16x32_bf16(qf[ks], bfK, s[n], 0, 0, 0);
            }
        }

        const bool diag = (jt == it);
        #pragma unroll
        for (int r = 0; r < 4; ++r) {
            int qrow = w * 16 + fg * 4 + r;
            float sv[4];
            float pm = -INFINITY;
            #pragma unroll
            for (int n = 0; n < 4; ++n) {
                float vsc = s[n][r] * 0.125f;
                if (diag && (n * 16 + fr) > qrow) vsc = -INFINITY;
                sv[n] = vsc;
                pm = fmaxf(pm, vsc);
            }
            pm = fmaxf(pm, __shfl_xor(pm, 1));
            pm = fmaxf(pm, __shfl_xor(pm, 2));
            pm = fmaxf(pm, __shfl_xor(pm, 4));
            pm = fmaxf(pm, __shfl_xor(pm, 8));
            float mnew = fmaxf(m_run[r], pm);
            float corr = __expf(m_run[r] - mnew);
            float rs = 0.0f;
            #pragma unroll
            for (int n = 0; n < 4; ++n) {
                float pv = __expf(sv[n] - mnew);
                rs += pv;
                Ps[w][fg * 4 + r][n * 16 + fr] = f2b(pv);
            }
            rs += __shfl_xor(rs, 1);
            rs += __shfl_xor(rs, 2);
            rs += __shfl_xor(rs, 4);
            rs += __shfl_xor(rs, 8);
            l_run[r] = l_run[r] * corr + rs;
            m_run[r] = mnew;
            #pragma unroll
            for (int n = 0; n < 4; ++n) o[n][r] *= corr;
        }

        #pragma unroll
        for (int ks = 0; ks < 2; ++ks) {
            short8 pa = *reinterpret_cast<const short8*>(&Ps[w][fr][ks * 32 + fg * 8]);
            #pragma unroll
            for (int n = 0; n < 4; ++n) {
                short8 vb = *reinterpret_cast<const short8*>(&Vt[n * 16 + fr][ks * 32 + fg * 8]);
                o[n] = __builtin_amdgcn_mfma_f32_16x16x32_bf16(pa, vb, o[n], 0, 0, 0);
            }
        }
    }

    #pragma unroll
    for (int r = 0; r < 4; ++r) {
        float inv = 1.0f / l_run[r];
        int qrow = it * 64 + w * 16 + fg * 4 + r;
        #pragma unroll
        for (int n = 0; n < 4; ++n)
            concatb[(size_t)qrow * DMODEL + h * DHEAD + n * 16 + fr] = f2b(o[n][r] * inv);
    }
}

// ---------------- fused partial-reduce + LayerNorm ----------------
// v = base + (RELUB ? relu(sum(P) + bias2) : sum(P)); out = LN(v)
template<int NPART, int RELUB, int DUAL>
__global__ __launch_bounds__(256) void ln_fuse(
    const float* __restrict__ P, size_t pstride,
    const float* __restrict__ base,
    const float* __restrict__ bias2,
    const float* __restrict__ g, const float* __restrict__ b,
    float* __restrict__ out, u16* __restrict__ outb)
{
    int row = blockIdx.x, tid = threadIdx.x;
    __shared__ float red[256];
    size_t off = (size_t)row * DMODEL + tid * 4;

    float4 acc = *reinterpret_cast<const float4*>(P + off);
    #pragma unroll
    for (int p = 1; p < NPART; ++p) {
        float4 t = *reinterpret_cast<const float4*>(P + (size_t)p * pstride + off);
        acc.x += t.x; acc.y += t.y; acc.z += t.z; acc.w += t.w;
    }
    if (RELUB) {
        float4 bb = *reinterpret_cast<const float4*>(bias2 + tid * 4);
        acc.x = fmaxf(acc.x + bb.x, 0.0f); acc.y = fmaxf(acc.y + bb.y, 0.0f);
        acc.z = fmaxf(acc.z + bb.z, 0.0f); acc.w = fmaxf(acc.w + bb.w, 0.0f);
    }
    float4 bs = *reinterpret_cast<const float4*>(base + off);
    float vals[4] = {acc.x + bs.x, acc.y + bs.y, acc.z + bs.z, acc.w + bs.w};

    float s = vals[0] + vals[1] + vals[2] + vals[3];
    red[tid] = s; __syncthreads();
    for (int st = 128; st > 0; st >>= 1) { if (tid < st) red[tid] += red[tid + st]; __syncthreads(); }
    float mu = red[0] * (1.0f / DMODEL);
    __syncthreads();

    float vs = 0.0f;
    #pragma unroll
    for (int i = 0; i < 4; ++i) { float d = vals[i] - mu; vs += d * d; }
    red[tid] = vs; __syncthreads();
    for (int st = 128; st > 0; st >>= 1) { if (tid < st) red[tid] += red[tid + st]; __syncthreads(); }
    float rstd = rsqrtf(red[0] * (1.0f / DMODEL) + LNEPS);

    float4 gv = *reinterpret_cast<const float4*>(g + tid * 4);
    float4 bv = *reinterpret_cast<const float4*>(b + tid * 4);
    float gs[4] = {gv.x, gv.y, gv.z, gv.w};
    float bsc[4] = {bv.x, bv.y, bv.z, bv.w};
    #pragma unroll
    for (int i = 0; i < 4; ++i) {
        float r = (vals[i] - mu) * rstd * gs[i] + bsc[i];
        out[off + i] = r;
        if (DUAL) outb[off + i] = f2b(r);
    }
}

// ---------------- launch ----------------
extern "C" void kernel_launch(void* const* d_in, const int* in_sizes, int n_in,
                              void* d_out, int out_size, void* d_ws, size_t ws_size,
                              hipStream_t stream)
{
    const float* x    = (const float*)d_in[0];
    const float* wq   = (const float*)d_in[1];
    const float* wk   = (const float*)d_in[2];
    const float* wv   = (const float*)d_in[3];
    const float* wo   = (const float*)d_in[4];
    const float* ln1g = (const float*)d_in[5];
    const float* ln1b = (const float*)d_in[6];
    const float* w1   = (const float*)d_in[7];
    const float* b1   = (const float*)d_in[8];
    const float* w2   = (const float*)d_in[9];
    const float* b2   = (const float*)d_in[10];
    const float* ln2g = (const float*)d_in[11];
    const float* ln2b = (const float*)d_in[12];
    float* out = (float*)d_out;

    // 64 MB workspace plan (time-sliced):
    //  [0,8)   w2T          (persists to ffn2)
    //  [8,16)  h1           (LN1 -> LN2)
    //  [16,32) P01 oproj partials -> then ff1b
    //  [32,64) wqkvT/woT/w1T/xb/qkvb early -> then FP (ffn2 partials x4)
    char* ws = (char*)d_ws;
    const size_t MB = 1024 * 1024;
    u16*   w2T     = (u16*)  (ws + 0 * MB);
    float* h1      = (float*)(ws + 8 * MB);
    float* P01     = (float*)(ws + 16 * MB);  // 2 x 8 MB
    u16*   ff1b    = (u16*)  (ws + 16 * MB);  // after LN1
    float* FP      = (float*)(ws + 32 * MB);  // 4 x 8 MB (ffn2 partials)
    u16*   wqkvT   = (u16*)  (ws + 32 * MB);
    u16*   woT     = (u16*)  (ws + 38 * MB);
    u16*   w1T     = (u16*)  (ws + 40 * MB);
    u16*   xb      = (u16*)  (ws + 48 * MB);
    u16*   concatb = (u16*)  (ws + 48 * MB);  // after xb dead
    u16*   h1b     = (u16*)  (ws + 48 * MB);  // after concatb dead
    u16*   qkvb    = (u16*)  (ws + 52 * MB);

    const size_t PSTRIDE = (size_t)NTOK * DMODEL;   // 2M elements

    dim3 blk(256);

    cast_f32_bf16<<<dim3(NTOK * DMODEL / 1024), blk, 0, stream>>>(x, xb, NTOK * DMODEL);
    cast_wqkv<<<dim3(2, 32, 48), blk, 0, stream>>>(wq, wk, wv, wqkvT);
    transpose_cast<<<dim3(32, 32),  blk, 0, stream>>>(wo, DMODEL, woT, DMODEL);
    transpose_cast<<<dim3(128, 32), blk, 0, stream>>>(w1, DFF, w1T, DMODEL);
    transpose_cast<<<dim3(32, 128), blk, 0, stream>>>(w2, DMODEL, w2T, DFF);

    // qkvb = bf16(xb @ wqkvT^T)
    mfma_gemm<0,0,0,1,1><<<dim3(24, 16), blk, 0, stream>>>(
        xb, DMODEL, wqkvT, DMODEL, qkvb, 3 * DMODEL, DMODEL, nullptr, nullptr, 0, 0);
    flash_attn_mfma<<<dim3(NTOK / 64, NHEAD), blk, 0, stream>>>(qkvb, concatb);
    // oproj split-K=2: P01[z] = concatb @ woT^T (chunk z)
    mfma_gemm<0,0,0,0,2><<<dim3(8, 16, 2), blk, 0, stream>>>(
        concatb, DMODEL, woT, DMODEL, P01, DMODEL, 512, nullptr, nullptr, 0, PSTRIDE);
    // LN1: h1 = LN(P0+P1+x), dual bf16
    ln_fuse<2,0,1><<<dim3(NTOK), blk, 0, stream>>>(
        P01, PSTRIDE, x, nullptr, ln1g, ln1b, h1, h1b);
    // ff1 = relu(h1b @ w1T^T + b1) -> bf16
    mfma_gemm<1,1,0,1,1><<<dim3(32, 16), blk, 0, stream>>>(
        h1b, DMODEL, w1T, DMODEL, ff1b, DFF, DMODEL, b1, nullptr, 0, 0);
    // ffn2 split-K=4: FP[z] = ff1b @ w2T^T (chunk z)
    mfma_gemm<0,0,0,0,4><<<dim3(8, 16, 4), blk, 0, stream>>>(
        ff1b, DFF, w2T, DFF, FP, DMODEL, 1024, nullptr, nullptr, 0, PSTRIDE);
    // LN2: out = LN(h1 + relu(sum(FP)+b2))
    ln_fuse<4,1,0><<<dim3(NTOK), blk, 0, stream>>>(
        FP, PSTRIDE, h1, b2, ln2g, ln2b, out, nullptr);
}

// Round 6
// 200.098 us; speedup vs baseline: 14.9839x; 1.1058x over previous
//
#include <hip/hip_runtime.h>
#include <math.h>

// TransformerBlock N=2048, D=1024, H=16, DK=DV=64, FF=4096.
// Round 6: flash attention fixes — (a) complementary-pair block remap for
// causal load balance, (b) K/V register prefetch (async-stage, T14),
// (c) Vt k-block XOR swizzle (kills 8-way store conflicts), (d) setprio.

#define NTOK   2048
#define DMODEL 1024
#define NHEAD  16
#define DHEAD  64
#define DFF    4096
#define LNEPS  1e-5f

typedef unsigned int   u32;
typedef unsigned short u16;
typedef __attribute__((ext_vector_type(8))) short short8;
typedef __attribute__((ext_vector_type(4))) float f32x4;

__device__ __forceinline__ u16 f2b(float f) {
    u32 b = __float_as_uint(f);
    b += 0x7FFFu + ((b >> 16) & 1u);   // RNE
    return (u16)(b >> 16);
}

#define AS1(p) ((const __attribute__((address_space(1))) u32*)(p))
#define AS3(p) ((__attribute__((address_space(3))) u32*)(p))

// ---------------- bf16 MFMA GEMM, 128x128 tile, BK=32, 2-phase dbuf --------
template<int RELU, int BIAS, int RESID, int OUT_BF16, int SPLITK>
__global__ __launch_bounds__(256) void mfma_gemm(
    const u16* __restrict__ A, int lda,
    const u16* __restrict__ Bt, int ldbt,
    void* __restrict__ Cp, int ldc, int Kc,
    const float* __restrict__ bias,
    const float* __restrict__ resid, int ldr,
    size_t pstride)
{
    __shared__ u16 As[2][128 * 32];
    __shared__ u16 Bs[2][128 * 32];

    const int tid = threadIdx.x;
    const int l = tid & 63, w = tid >> 6;
    const int row0 = blockIdx.y * 128, col0 = blockIdx.x * 128;
    const int kbase = (SPLITK > 1) ? blockIdx.z * Kc : 0;

    f32x4 acc[4][4];
    #pragma unroll
    for (int m = 0; m < 4; ++m)
        #pragma unroll
        for (int n = 0; n < 4; ++n)
            acc[m][n] = (f32x4){0.f, 0.f, 0.f, 0.f};

    const int srow = w * 32 + (l >> 2);
    const int skk  = (l & 3) * 8;
    const u16* Ag = A  + (size_t)(row0 + srow) * lda  + kbase + skk;
    const u16* Bg = Bt + (size_t)(col0 + srow) * ldbt + kbase + skk;

    const int fr  = l & 15;
    const int fk  = (l >> 4) * 8;
    const int ar0 = (w >> 1) * 64;
    const int bc0 = (w & 1) * 64;

    auto STAGE = [&](int buf, int k0) {
        char* AsB = (char*)&As[buf][0] + w * 2048;
        char* BsB = (char*)&Bs[buf][0] + w * 2048;
        __builtin_amdgcn_global_load_lds(AS1(Ag + k0),                     AS3(AsB),        16, 0, 0);
        __builtin_amdgcn_global_load_lds(AS1(Ag + k0 + (size_t)16 * lda),  AS3(AsB + 1024), 16, 0, 0);
        __builtin_amdgcn_global_load_lds(AS1(Bg + k0),                     AS3(BsB),        16, 0, 0);
        __builtin_amdgcn_global_load_lds(AS1(Bg + k0 + (size_t)16 * ldbt), AS3(BsB + 1024), 16, 0, 0);
    };

    STAGE(0, 0);
    int cur = 0;
    for (int k0 = 0; k0 < Kc; k0 += 32) {
        __syncthreads();
        if (k0 + 32 < Kc) STAGE(cur ^ 1, k0 + 32);

        short8 af[4], bfr[4];
        #pragma unroll
        for (int m = 0; m < 4; ++m)
            af[m] = *reinterpret_cast<const short8*>(&As[cur][(ar0 + m * 16 + fr) * 32 + fk]);
        #pragma unroll
        for (int n = 0; n < 4; ++n)
            bfr[n] = *reinterpret_cast<const short8*>(&Bs[cur][(bc0 + n * 16 + fr) * 32 + fk]);
        #pragma unroll
        for (int m = 0; m < 4; ++m)
            #pragma unroll
            for (int n = 0; n < 4; ++n)
                acc[m][n] = __builtin_amdgcn_mfma_f32_16x16x32_bf16(af[m], bfr[n], acc[m][n], 0, 0, 0);
        cur ^= 1;
    }

    if (SPLITK > 1) {
        float* Pp = (float*)Cp + blockIdx.z * pstride;
        #pragma unroll
        for (int m = 0; m < 4; ++m)
            #pragma unroll
            for (int n = 0; n < 4; ++n)
                #pragma unroll
                for (int r = 0; r < 4; ++r) {
                    int row = row0 + ar0 + m * 16 + (l >> 4) * 4 + r;
                    int col = col0 + bc0 + n * 16 + (l & 15);
                    Pp[(size_t)row * ldc + col] = acc[m][n][r];
                }
        return;
    }

    #pragma unroll
    for (int m = 0; m < 4; ++m) {
        #pragma unroll
        for (int n = 0; n < 4; ++n) {
            #pragma unroll
            for (int r = 0; r < 4; ++r) {
                int row = row0 + ar0 + m * 16 + (l >> 4) * 4 + r;
                int col = col0 + bc0 + n * 16 + (l & 15);
                float val = acc[m][n][r];
                if (BIAS)  val += bias[col];
                if (RESID) val += resid[(size_t)row * ldr + col];
                if (RELU)  val = fmaxf(val, 0.0f);
                if (OUT_BF16) ((u16*)Cp)[(size_t)row * ldc + col] = f2b(val);
                else          ((float*)Cp)[(size_t)row * ldc + col] = val;
            }
        }
    }
}

// ---------------- cast / transpose helpers ----------------
__global__ __launch_bounds__(256) void cast_f32_bf16(const float* __restrict__ in,
                                                     u16* __restrict__ out, int n)
{
    int i = (blockIdx.x * 256 + threadIdx.x) * 4;
    if (i + 3 < n) {
        float4 v = *reinterpret_cast<const float4*>(in + i);
        ushort4 o;
        o.x = f2b(v.x); o.y = f2b(v.y); o.z = f2b(v.z); o.w = f2b(v.w);
        *reinterpret_cast<ushort4*>(out + i) = o;
    }
}

__device__ __forceinline__ void transpose_body(const float* __restrict__ in, int ldin,
                                               u16* __restrict__ out, int ldout)
{
    __shared__ float tile[32][33];
    int r0 = blockIdx.y * 32, c0 = blockIdx.x * 32;
    int tx = threadIdx.x & 31, ty = threadIdx.x >> 5;
    #pragma unroll
    for (int i = 0; i < 4; ++i) {
        int r = ty + i * 8;
        tile[r][tx] = in[(size_t)(r0 + r) * ldin + c0 + tx];
    }
    __syncthreads();
    #pragma unroll
    for (int i = 0; i < 4; ++i) {
        int rr = ty + i * 8;
        out[(size_t)(c0 + rr) * ldout + r0 + tx] = f2b(tile[tx][rr]);
    }
}

__global__ __launch_bounds__(256) void transpose_cast(const float* __restrict__ in, int ldin,
                                                      u16* __restrict__ out, int ldout)
{
    transpose_body(in, ldin, out, ldout);
}

__global__ __launch_bounds__(256) void cast_wqkv(
    const float* __restrict__ wq, const float* __restrict__ wk, const float* __restrict__ wv,
    u16* __restrict__ outT)
{
    int z = blockIdx.z, p = z >> 4, h = z & 15;
    const float* in = (p == 0 ? wq : p == 1 ? wk : wv) + (size_t)h * DMODEL * DHEAD;
    u16* out = outT + (size_t)(p * 1024 + h * 64) * DMODEL;
    transpose_body(in, DHEAD, out, DMODEL);
}

// ---------------- MFMA flash attention (balanced + prefetch + swizzle) -----
// Linear grid of 512: bid<256 -> it=bid>>3, h=bid&7; bid>=256 -> it=31-((bid-256)>>3),
// h=8+(bid&7). Co-resident pairs (bid, bid+256) sum to 33 kv-tiles.
__global__ __launch_bounds__(256) void flash_attn_mfma(
    const u16* __restrict__ qkvb, u16* __restrict__ concatb)
{
    const int bid = blockIdx.x;
    const int lo = bid & 255;
    int it = lo >> 3;
    int h  = lo & 7;
    if (bid >= 256) { it = 31 - it; h += 8; }

    const u16* qh = qkvb + h * DHEAD;
    const u16* kh = qkvb + DMODEL + h * DHEAD;
    const u16* vh = qkvb + 2 * DMODEL + h * DHEAD;
    const int LDQ = 3 * DMODEL;

    __shared__ u16 Ks[64][72];       // K rows (pad-72: 2-way max on frag reads)
    __shared__ u16 Vt[64][72];       // V^T, k-blocks XOR-swizzled by (dv>>3)&7
    __shared__ u16 Ps[4][16][72];    // per-wave P tile

    const int tid = threadIdx.x;
    const int l = tid & 63, w = tid >> 6;
    const int fr = l & 15, fg = l >> 4;

    // Q fragments
    short8 qf[2];
    {
        const u16* qp = qh + (size_t)(it * 64 + w * 16 + fr) * LDQ + fg * 8;
        qf[0] = *reinterpret_cast<const short8*>(qp);
        qf[1] = *reinterpret_cast<const short8*>(qp + 32);
    }

    // staging geometry
    const int kr = tid >> 2, kc = (tid & 3) * 16;       // K: row, col
    const int vp = tid >> 3, vc = (tid & 7) * 8;        // V: row-pair, dv base
    char* VtB = (char*)Vt;

    short8 kf0, kf1, vf0, vf1;
    auto PREFETCH = [&](int jt) {
        const u16* kg = kh + (size_t)(jt * 64 + kr) * LDQ + kc;
        kf0 = *reinterpret_cast<const short8*>(kg);
        kf1 = *reinterpret_cast<const short8*>(kg + 8);
        const u16* vg = vh + (size_t)(jt * 64 + 2 * vp) * LDQ + vc;
        vf0 = *reinterpret_cast<const short8*>(vg);
        vf1 = *reinterpret_cast<const short8*>(vg + LDQ);
    };

    f32x4 o[4];
    #pragma unroll
    for (int n = 0; n < 4; ++n) o[n] = (f32x4){0.f, 0.f, 0.f, 0.f};
    float m_run[4], l_run[4];
    #pragma unroll
    for (int r = 0; r < 4; ++r) { m_run[r] = -INFINITY; l_run[r] = 0.0f; }

    PREFETCH(0);

    for (int jt = 0; jt <= it; ++jt) {
        __syncthreads();   // previous tile's Ks/Vt readers done
        // commit prefetched K/V to LDS
        *reinterpret_cast<short8*>(&Ks[kr][kc])     = kf0;
        *reinterpret_cast<short8*>(&Ks[kr][kc + 8]) = kf1;
        #pragma unroll
        for (int i = 0; i < 8; ++i) {
            u32 word = (u32)(u16)vf0[i] | ((u32)(u16)vf1[i] << 16);
            int dv = vc + i;
            int off = 144 * dv + 16 * ((vp >> 2) ^ ((dv >> 3) & 7)) + 4 * (vp & 3);
            *reinterpret_cast<u32*>(VtB + off) = word;
        }
        if (jt < it) PREFETCH(jt + 1);   // global latency hides under compute
        __syncthreads();

        // S = Q @ K^T
        f32x4 s[4];
        #pragma unroll
        for (int n = 0; n < 4; ++n) s[n] = (f32x4){0.f, 0.f, 0.f, 0.f};
        __builtin_amdgcn_s_setprio(1);
        #pragma unroll
        for (int n = 0; n < 4; ++n) {
            #pragma unroll
            for (int ks = 0; ks < 2; ++ks) {
                short8 bfK = *reinterpret_cast<const short8*>(&Ks[n * 16 + fr][ks * 32 + fg * 8]);
                s[n] = __builtin_amdgcn_mfma_f32_16x16x32_bf16(qf[ks], bfK, s[n], 0, 0, 0);
            }
        }
        __builtin_amdgcn_s_setprio(0);

        // online softmax
        const bool diag = (jt == it);
        #pragma unroll
        for (int r = 0; r < 4; ++r) {
            int qrow = w * 16 + fg * 4 + r;
            float sv[4];
            float pm = -INFINITY;
            #pragma unroll
            for (int n = 0; n < 4; ++n) {
                float vsc = s[n][r] * 0.125f;
                if (diag && (n * 16 + fr) > qrow) vsc = -INFINITY;
                sv[n] = vsc;
                pm = fmaxf(pm, vsc);
            }
            pm = fmaxf(pm, __shfl_xor(pm, 1));
            pm = fmaxf(pm, __shfl_xor(pm, 2));
            pm = fmaxf(pm, __shfl_xor(pm, 4));
            pm = fmaxf(pm, __shfl_xor(pm, 8));
            float mnew = fmaxf(m_run[r], pm);
            float corr = __expf(m_run[r] - mnew);
            float rs = 0.0f;
            #pragma unroll
            for (int n = 0; n < 4; ++n) {
                float pv = __expf(sv[n] - mnew);
                rs += pv;
                Ps[w][fg * 4 + r][n * 16 + fr] = f2b(pv);
            }
            rs += __shfl_xor(rs, 1);
            rs += __shfl_xor(rs, 2);
            rs += __shfl_xor(rs, 4);
            rs += __shfl_xor(rs, 8);
            l_run[r] = l_run[r] * corr + rs;
            m_run[r] = mnew;
            #pragma unroll
            for (int n = 0; n < 4; ++n) o[n][r] *= corr;
        }

        // O += P @ V  (Vt reads use the same XOR swizzle)
        __builtin_amdgcn_s_setprio(1);
        #pragma unroll
        for (int ks = 0; ks < 2; ++ks) {
            short8 pa = *reinterpret_cast<const short8*>(&Ps[w][fr][ks * 32 + fg * 8]);
            #pragma unroll
            for (int n = 0; n < 4; ++n) {
                int dv = n * 16 + fr;
                const short8* vbp = reinterpret_cast<const short8*>(
                    VtB + 144 * dv + 16 * ((ks * 4 + fg) ^ ((dv >> 3) & 7)));
                o[n] = __builtin_amdgcn_mfma_f32_16x16x32_bf16(pa, *vbp, o[n], 0, 0, 0);
            }
        }
        __builtin_amdgcn_s_setprio(0);
    }

    #pragma unroll
    for (int r = 0; r < 4; ++r) {
        float inv = 1.0f / l_run[r];
        int qrow = it * 64 + w * 16 + fg * 4 + r;
        #pragma unroll
        for (int n = 0; n < 4; ++n)
            concatb[(size_t)qrow * DMODEL + h * DHEAD + n * 16 + fr] = f2b(o[n][r] * inv);
    }
}

// ---------------- fused partial-reduce + LayerNorm ----------------
template<int NPART, int RELUB, int DUAL>
__global__ __launch_bounds__(256) void ln_fuse(
    const float* __restrict__ P, size_t pstride,
    const float* __restrict__ base,
    const float* __restrict__ bias2,
    const float* __restrict__ g, const float* __restrict__ b,
    float* __restrict__ out, u16* __restrict__ outb)
{
    int row = blockIdx.x, tid = threadIdx.x;
    __shared__ float red[256];
    size_t off = (size_t)row * DMODEL + tid * 4;

    float4 acc = *reinterpret_cast<const float4*>(P + off);
    #pragma unroll
    for (int p = 1; p < NPART; ++p) {
        float4 t = *reinterpret_cast<const float4*>(P + (size_t)p * pstride + off);
        acc.x += t.x; acc.y += t.y; acc.z += t.z; acc.w += t.w;
    }
    if (RELUB) {
        float4 bb = *reinterpret_cast<const float4*>(bias2 + tid * 4);
        acc.x = fmaxf(acc.x + bb.x, 0.0f); acc.y = fmaxf(acc.y + bb.y, 0.0f);
        acc.z = fmaxf(acc.z + bb.z, 0.0f); acc.w = fmaxf(acc.w + bb.w, 0.0f);
    }
    float4 bs = *reinterpret_cast<const float4*>(base + off);
    float vals[4] = {acc.x + bs.x, acc.y + bs.y, acc.z + bs.z, acc.w + bs.w};

    float s = vals[0] + vals[1] + vals[2] + vals[3];
    red[tid] = s; __syncthreads();
    for (int st = 128; st > 0; st >>= 1) { if (tid < st) red[tid] += red[tid + st]; __syncthreads(); }
    float mu = red[0] * (1.0f / DMODEL);
    __syncthreads();

    float vs = 0.0f;
    #pragma unroll
    for (int i = 0; i < 4; ++i) { float d = vals[i] - mu; vs += d * d; }
    red[tid] = vs; __syncthreads();
    for (int st = 128; st > 0; st >>= 1) { if (tid < st) red[tid] += red[tid + st]; __syncthreads(); }
    float rstd = rsqrtf(red[0] * (1.0f / DMODEL) + LNEPS);

    float4 gv = *reinterpret_cast<const float4*>(g + tid * 4);
    float4 bv = *reinterpret_cast<const float4*>(b + tid * 4);
    float gs[4] = {gv.x, gv.y, gv.z, gv.w};
    float bsc[4] = {bv.x, bv.y, bv.z, bv.w};
    #pragma unroll
    for (int i = 0; i < 4; ++i) {
        float r = (vals[i] - mu) * rstd * gs[i] + bsc[i];
        out[off + i] = r;
        if (DUAL) outb[off + i] = f2b(r);
    }
}

// ---------------- launch ----------------
extern "C" void kernel_launch(void* const* d_in, const int* in_sizes, int n_in,
                              void* d_out, int out_size, void* d_ws, size_t ws_size,
                              hipStream_t stream)
{
    const float* x    = (const float*)d_in[0];
    const float* wq   = (const float*)d_in[1];
    const float* wk   = (const float*)d_in[2];
    const float* wv   = (const float*)d_in[3];
    const float* wo   = (const float*)d_in[4];
    const float* ln1g = (const float*)d_in[5];
    const float* ln1b = (const float*)d_in[6];
    const float* w1   = (const float*)d_in[7];
    const float* b1   = (const float*)d_in[8];
    const float* w2   = (const float*)d_in[9];
    const float* b2   = (const float*)d_in[10];
    const float* ln2g = (const float*)d_in[11];
    const float* ln2b = (const float*)d_in[12];
    float* out = (float*)d_out;

    char* ws = (char*)d_ws;
    const size_t MB = 1024 * 1024;
    u16*   w2T     = (u16*)  (ws + 0 * MB);
    float* h1      = (float*)(ws + 8 * MB);
    float* P01     = (float*)(ws + 16 * MB);  // 2 x 8 MB (oproj partials)
    u16*   ff1b    = (u16*)  (ws + 16 * MB);  // after LN1
    float* FP      = (float*)(ws + 32 * MB);  // 4 x 8 MB (ffn2 partials)
    u16*   wqkvT   = (u16*)  (ws + 32 * MB);
    u16*   woT     = (u16*)  (ws + 38 * MB);
    u16*   w1T     = (u16*)  (ws + 40 * MB);
    u16*   xb      = (u16*)  (ws + 48 * MB);
    u16*   concatb = (u16*)  (ws + 48 * MB);
    u16*   h1b     = (u16*)  (ws + 48 * MB);
    u16*   qkvb    = (u16*)  (ws + 52 * MB);

    const size_t PSTRIDE = (size_t)NTOK * DMODEL;

    dim3 blk(256);

    cast_f32_bf16<<<dim3(NTOK * DMODEL / 1024), blk, 0, stream>>>(x, xb, NTOK * DMODEL);
    cast_wqkv<<<dim3(2, 32, 48), blk, 0, stream>>>(wq, wk, wv, wqkvT);
    transpose_cast<<<dim3(32, 32),  blk, 0, stream>>>(wo, DMODEL, woT, DMODEL);
    transpose_cast<<<dim3(128, 32), blk, 0, stream>>>(w1, DFF, w1T, DMODEL);
    transpose_cast<<<dim3(32, 128), blk, 0, stream>>>(w2, DMODEL, w2T, DFF);

    mfma_gemm<0,0,0,1,1><<<dim3(24, 16), blk, 0, stream>>>(
        xb, DMODEL, wqkvT, DMODEL, qkvb, 3 * DMODEL, DMODEL, nullptr, nullptr, 0, 0);
    flash_attn_mfma<<<dim3(512), blk, 0, stream>>>(qkvb, concatb);
    mfma_gemm<0,0,0,0,2><<<dim3(8, 16, 2), blk, 0, stream>>>(
        concatb, DMODEL, woT, DMODEL, P01, DMODEL, 512, nullptr, nullptr, 0, PSTRIDE);
    ln_fuse<2,0,1><<<dim3(NTOK), blk, 0, stream>>>(
        P01, PSTRIDE, x, nullptr, ln1g, ln1b, h1, h1b);
    mfma_gemm<1,1,0,1,1><<<dim3(32, 16), blk, 0, stream>>>(
        h1b, DMODEL, w1T, DMODEL, ff1b, DFF, DMODEL, b1, nullptr, 0, 0);
    mfma_gemm<0,0,0,0,4><<<dim3(8, 16, 4), blk, 0, stream>>>(
        ff1b, DFF, w2T, DFF, FP, DMODEL, 1024, nullptr, nullptr, 0, PSTRIDE);
    ln_fuse<4,1,0><<<dim3(NTOK), blk, 0, stream>>>(
        FP, PSTRIDE, h1, b2, ln2g, ln2b, out, nullptr);
}